// Round 3
// baseline (455.457 us; speedup 1.0000x reference)
//
#include <hip/hip_runtime.h>
#include <hip/hip_bf16.h>
#include <stdint.h>

#define NTOK 4096
#define DM   1024
#define NH   16
#define DH   64
#define SCL  0.1803368801111129f   /* 0.125 * log2(e) */
#define LOG2E 1.4426950408889634f

typedef __attribute__((ext_vector_type(8)))  short bf16x8;
typedef __attribute__((ext_vector_type(4)))  float f32x4;
typedef __attribute__((ext_vector_type(16))) float f32x16;
typedef __attribute__((ext_vector_type(4)))  unsigned short us4;

__device__ inline unsigned short f2bf(float f) {
  union { float f; unsigned int u; } a;
  a.f = f;
  unsigned int u = a.u;
  u += 0x7fffu + ((u >> 16) & 1u);
  return (unsigned short)(u >> 16);
}

__device__ inline unsigned int cvtpk_bf16(float lo, float hi) {
  unsigned int r;
  asm("v_cvt_pk_bf16_f32 %0, %1, %2" : "=v"(r) : "v"(lo), "v"(hi));
  return r;
}

__device__ inline void gload_lds16(const void* gsrc, void* ldst) {
  __builtin_amdgcn_global_load_lds(
      (const __attribute__((address_space(1))) void*)(uintptr_t)gsrc,
      (__attribute__((address_space(3))) void*)(unsigned int)(uintptr_t)ldst,
      16, 0, 0);
}

// ---------------- f32 -> bf16 conversion ----------------
__global__ void cvt_kernel(const float* __restrict__ in,
                           unsigned short* __restrict__ out, int n4) {
  int i = blockIdx.x * 256 + threadIdx.x;
  if (i < n4) {
    float4 v = ((const float4*)in)[i];
    us4 o;
    o[0] = f2bf(v.x); o[1] = f2bf(v.y); o[2] = f2bf(v.z); o[3] = f2bf(v.w);
    ((us4*)out)[i] = o;
  }
}

// ---------------- h permute: hperm[t*32 + hi*16 + r] = log2e*h[key] --------
__global__ void hprep_kernel(const float* __restrict__ h,
                             float* __restrict__ hperm) {
  int i = blockIdx.x * 256 + threadIdx.x;      // 0..4095
  int r  = i & 15;
  int hi = (i >> 4) & 1;
  int t  = i >> 5;
  int key = t * 32 + (r & 3) + 8 * (r >> 2) + 4 * hi;
  hperm[i] = LOG2E * h[key];                   // GAMMA = 1
}

// ---------------- fused QKV GEMM: A[4096][1024] x Wpack[3072][1024]^T ------
__global__ __launch_bounds__(256)
void gemm_qkv(const unsigned short* __restrict__ A,
              const unsigned short* __restrict__ B,
              const float* __restrict__ bq, const float* __restrict__ bk,
              const float* __restrict__ bv,
              unsigned short* __restrict__ Qb, unsigned short* __restrict__ Kb,
              unsigned short* __restrict__ Vt)
{
  const int tid  = threadIdx.x;
  const int wid  = tid >> 6;
  const int lane = tid & 63;
  const int bn = blockIdx.x * 128;
  const int bm = blockIdx.y * 128;
  const int wr = wid >> 1;
  const int wc = wid & 1;

  __shared__ __align__(16) unsigned short As[128 * 32];
  __shared__ __align__(16) unsigned short Bs[128 * 32];

  f32x4 acc[4][4];
#pragma unroll
  for (int i = 0; i < 4; i++)
#pragma unroll
    for (int j = 0; j < 4; j++) acc[i][j] = f32x4{0.f, 0.f, 0.f, 0.f};

  const int fr = lane & 15;
  const int fk = (lane >> 4) * 8;
  const int srow = lane >> 2;
  const int scol = (lane & 3) * 8;

  for (int k0 = 0; k0 < DM; k0 += 32) {
#pragma unroll
    for (int c = 0; c < 2; ++c) {
      const int chunk = wid * 2 + c;
      gload_lds16(A + (size_t)(bm + chunk * 16 + srow) * DM + k0 + scol,
                  &As[chunk * 512]);
      gload_lds16(B + (size_t)(bn + chunk * 16 + srow) * DM + k0 + scol,
                  &Bs[chunk * 512]);
    }
    __syncthreads();
    bf16x8 af[4], bfr[4];
#pragma unroll
    for (int i = 0; i < 4; i++)
      af[i] = *(const bf16x8*)&As[(wr * 64 + i * 16 + fr) * 32 + fk];
#pragma unroll
    for (int j = 0; j < 4; j++)
      bfr[j] = *(const bf16x8*)&Bs[(wc * 64 + j * 16 + fr) * 32 + fk];
#pragma unroll
    for (int i = 0; i < 4; i++)
#pragma unroll
      for (int j = 0; j < 4; j++)
        acc[i][j] = __builtin_amdgcn_mfma_f32_16x16x32_bf16(af[i], bfr[j],
                                                            acc[i][j], 0, 0, 0);
    __syncthreads();
  }

  const int fq = lane >> 4;
  const int region = bn >> 10;                       // 0=Q 1=K 2=V
  const float* bias = (region == 0) ? bq : (region == 1) ? bk : bv;
  unsigned short* outp = (region == 0) ? Qb : Kb;
#pragma unroll
  for (int j = 0; j < 4; j++) {
    const int col = bn + wc * 64 + j * 16 + fr;
    const int cl  = col & 1023;
    const float bvx = bias[cl];
#pragma unroll
    for (int i = 0; i < 4; i++) {
      const int row0 = bm + wr * 64 + i * 16 + fq * 4;
      if (region < 2) {
#pragma unroll
        for (int r = 0; r < 4; r++)
          outp[(size_t)(row0 + r) * DM + cl] = f2bf(acc[i][j][r] + bvx);
      } else {
        us4 pk;
#pragma unroll
        for (int r = 0; r < 4; r++) pk[r] = f2bf(acc[i][j][r] + bvx);
        *(us4*)&Vt[(size_t)cl * NTOK + row0] = pk;
      }
    }
  }
}

// ---------------- final GEMM: out = AO x Wo^T + bo + x  (f32 out) ----------
__global__ __launch_bounds__(256)
void gemm_out(const unsigned short* __restrict__ A,
              const unsigned short* __restrict__ B,
              const float* __restrict__ bias,
              const float* __restrict__ resid,
              float* __restrict__ Cf)
{
  const int tid  = threadIdx.x;
  const int wid  = tid >> 6;
  const int lane = tid & 63;
  const int bn = blockIdx.x * 128;
  const int bm = blockIdx.y * 128;
  const int wr = wid >> 1;
  const int wc = wid & 1;

  __shared__ __align__(16) unsigned short As[128 * 32];
  __shared__ __align__(16) unsigned short Bs[128 * 32];

  f32x4 acc[4][4];
#pragma unroll
  for (int i = 0; i < 4; i++)
#pragma unroll
    for (int j = 0; j < 4; j++) acc[i][j] = f32x4{0.f, 0.f, 0.f, 0.f};

  const int fr = lane & 15;
  const int fk = (lane >> 4) * 8;
  const int srow = lane >> 2;
  const int scol = (lane & 3) * 8;

  for (int k0 = 0; k0 < DM; k0 += 32) {
#pragma unroll
    for (int c = 0; c < 2; ++c) {
      const int chunk = wid * 2 + c;
      gload_lds16(A + (size_t)(bm + chunk * 16 + srow) * DM + k0 + scol,
                  &As[chunk * 512]);
      gload_lds16(B + (size_t)(bn + chunk * 16 + srow) * DM + k0 + scol,
                  &Bs[chunk * 512]);
    }
    __syncthreads();
    bf16x8 af[4], bfr[4];
#pragma unroll
    for (int i = 0; i < 4; i++)
      af[i] = *(const bf16x8*)&As[(wr * 64 + i * 16 + fr) * 32 + fk];
#pragma unroll
    for (int j = 0; j < 4; j++)
      bfr[j] = *(const bf16x8*)&Bs[(wc * 64 + j * 16 + fr) * 32 + fk];
#pragma unroll
    for (int i = 0; i < 4; i++)
#pragma unroll
      for (int j = 0; j < 4; j++)
        acc[i][j] = __builtin_amdgcn_mfma_f32_16x16x32_bf16(af[i], bfr[j],
                                                            acc[i][j], 0, 0, 0);
    __syncthreads();
  }

  const int fq = lane >> 4;
#pragma unroll
  for (int j = 0; j < 4; j++) {
    const int col = bn + wc * 64 + j * 16 + fr;
    const float bvx = bias[col];
#pragma unroll
    for (int i = 0; i < 4; i++) {
      const int row0 = bm + wr * 64 + i * 16 + fq * 4;
#pragma unroll
      for (int r = 0; r < 4; r++) {
        const size_t idx = (size_t)(row0 + r) * DM + col;
        Cf[idx] = acc[i][j][r] + bvx + resid[idx];
      }
    }
  }
}

// ---------------- attention: swapped-QK^T 32x32, in-register softmax -------
// 4 waves/block each own a 1024-key quarter of the SAME 32 q rows;
// split-softmax merge through LDS at the end.
#define MFMA32(a, b, c) __builtin_amdgcn_mfma_f32_32x32x16_bf16(a, b, c, 0, 0, 0)

__global__ __launch_bounds__(256, 4)
void attn_kernel(const unsigned short* __restrict__ Q,
                 const unsigned short* __restrict__ K,
                 const unsigned short* __restrict__ Vt,
                 const float* __restrict__ hperm,
                 unsigned short* __restrict__ O)
{
  const int head = blockIdx.y;
  const int tid  = threadIdx.x;
  const int w    = tid >> 6;
  const int lane = tid & 63;
  const int c31  = lane & 31;
  const int hi   = lane >> 5;
  const int qb   = blockIdx.x * 32;

  __shared__ float osh[4][32 * 65];   // pad-65: conflict-free scalar access
  __shared__ float msh[4][32];
  __shared__ float lsh[4][32];

  // Q fragment (B-operand): lane holds Q[qb+c31][16c + 8*hi + j]
  const unsigned short* qp = Q + (size_t)(qb + c31) * DM + head * DH + hi * 8;
  const bf16x8 qf0 = *(const bf16x8*)(qp);
  const bf16x8 qf1 = *(const bf16x8*)(qp + 16);
  const bf16x8 qf2 = *(const bf16x8*)(qp + 32);
  const bf16x8 qf3 = *(const bf16x8*)(qp + 48);

  const int k0 = w * (NTOK / 4);                 // this wave's key range base
  const unsigned short* kp = K + (size_t)(k0 + c31) * DM + head * DH + hi * 8;
  const unsigned short* vp = Vt + (size_t)(head * DH + c31) * NTOK + k0 + hi * 8;
  const float* hp = hperm + k0 + hi * 16;

  f32x16 o0, o1;
#pragma unroll
  for (int i = 0; i < 16; i++) { o0[i] = 0.f; o1[i] = 0.f; }
  float m = -3.0e38f, l = 0.f;

  // preload tile 0: K fragments + bias
  bf16x8 kf0 = *(const bf16x8*)(kp);
  bf16x8 kf1 = *(const bf16x8*)(kp + 16);
  bf16x8 kf2 = *(const bf16x8*)(kp + 32);
  bf16x8 kf3 = *(const bf16x8*)(kp + 48);
  float4 hb0 = *(const float4*)(hp + 0);
  float4 hb1 = *(const float4*)(hp + 4);
  float4 hb2 = *(const float4*)(hp + 8);
  float4 hb3 = *(const float4*)(hp + 12);

  const int NT = NTOK / 4 / 32;                  // 32 tiles per wave
  for (int t = 0; t < NT; ++t) {
    const int kt = t * 32;
    const unsigned short* vb = vp + kt;
    const bf16x8 v00 = *(const bf16x8*)(vb);
    const bf16x8 v01 = *(const bf16x8*)(vb + 16);
    const bf16x8 v10 = *(const bf16x8*)(vb + (size_t)32 * NTOK);
    const bf16x8 v11 = *(const bf16x8*)(vb + (size_t)32 * NTOK + 16);

    // S^T[key][q] = K . Q^T
    f32x16 s;
#pragma unroll
    for (int i = 0; i < 16; i++) s[i] = 0.f;
    s = MFMA32(kf0, qf0, s);
    s = MFMA32(kf1, qf1, s);
    s = MFMA32(kf2, qf2, s);
    s = MFMA32(kf3, qf3, s);

    // prefetch next tile K + bias (within this wave's range)
    const int tn = (t + 1 < NT) ? t + 1 : t;
    const unsigned short* knp = kp + (size_t)tn * 32 * DM;
    const bf16x8 nf0 = *(const bf16x8*)(knp);
    const bf16x8 nf1 = *(const bf16x8*)(knp + 16);
    const bf16x8 nf2 = *(const bf16x8*)(knp + 32);
    const bf16x8 nf3 = *(const bf16x8*)(knp + 48);
    const float* hnp = hp + tn * 32;
    const float4 nh0 = *(const float4*)(hnp + 0);
    const float4 nh1 = *(const float4*)(hnp + 4);
    const float4 nh2 = *(const float4*)(hnp + 8);
    const float4 nh3 = *(const float4*)(hnp + 12);

    // logits in log2 domain: L = s*SCL - hb
    float Lv[16];
    Lv[0]  = fmaf(s[0],  SCL, -hb0.x); Lv[1]  = fmaf(s[1],  SCL, -hb0.y);
    Lv[2]  = fmaf(s[2],  SCL, -hb0.z); Lv[3]  = fmaf(s[3],  SCL, -hb0.w);
    Lv[4]  = fmaf(s[4],  SCL, -hb1.x); Lv[5]  = fmaf(s[5],  SCL, -hb1.y);
    Lv[6]  = fmaf(s[6],  SCL, -hb1.z); Lv[7]  = fmaf(s[7],  SCL, -hb1.w);
    Lv[8]  = fmaf(s[8],  SCL, -hb2.x); Lv[9]  = fmaf(s[9],  SCL, -hb2.y);
    Lv[10] = fmaf(s[10], SCL, -hb2.z); Lv[11] = fmaf(s[11], SCL, -hb2.w);
    Lv[12] = fmaf(s[12], SCL, -hb3.x); Lv[13] = fmaf(s[13], SCL, -hb3.y);
    Lv[14] = fmaf(s[14], SCL, -hb3.z); Lv[15] = fmaf(s[15], SCL, -hb3.w);

    float pm = fmaxf(fmaxf(fmaxf(Lv[0], Lv[1]), fmaxf(Lv[2], Lv[3])),
                     fmaxf(fmaxf(Lv[4], Lv[5]), fmaxf(Lv[6], Lv[7])));
    pm = fmaxf(pm, fmaxf(fmaxf(fmaxf(Lv[8], Lv[9]), fmaxf(Lv[10], Lv[11])),
                         fmaxf(fmaxf(Lv[12], Lv[13]), fmaxf(Lv[14], Lv[15]))));
    pm = fmaxf(pm, __shfl_xor(pm, 32, 64));

    // defer-max (T13)
    if (!__all(pm <= m + 8.0f)) {
      const float mn = fmaxf(m, pm);
      const float al = exp2f(m - mn);
      m = mn;
      l *= al;
#pragma unroll
      for (int i = 0; i < 16; i++) { o0[i] *= al; o1[i] *= al; }
    }

    float ps[16];
#pragma unroll
    for (int r = 0; r < 16; r++) ps[r] = exp2f(Lv[r] - m);
    float rs = (((ps[0] + ps[1]) + (ps[2] + ps[3])) +
                ((ps[4] + ps[5]) + (ps[6] + ps[7]))) +
               (((ps[8] + ps[9]) + (ps[10] + ps[11])) +
                ((ps[12] + ps[13]) + (ps[14] + ps[15])));
    rs += __shfl_xor(rs, 32, 64);
    l += rs;

    // pack P^T into B-fragments via cvt_pk + permlane32_swap (T12)
    unsigned int X1 = cvtpk_bf16(ps[0],  ps[1]);
    unsigned int X2 = cvtpk_bf16(ps[2],  ps[3]);
    unsigned int Y1 = cvtpk_bf16(ps[4],  ps[5]);
    unsigned int Y2 = cvtpk_bf16(ps[6],  ps[7]);
    asm("v_permlane32_swap_b32 %0, %1" : "+v"(X1), "+v"(Y1));
    asm("v_permlane32_swap_b32 %0, %1" : "+v"(X2), "+v"(Y2));
    unsigned int X3 = cvtpk_bf16(ps[8],  ps[9]);
    unsigned int X4 = cvtpk_bf16(ps[10], ps[11]);
    unsigned int Y3 = cvtpk_bf16(ps[12], ps[13]);
    unsigned int Y4 = cvtpk_bf16(ps[14], ps[15]);
    asm("v_permlane32_swap_b32 %0, %1" : "+v"(X3), "+v"(Y3));
    asm("v_permlane32_swap_b32 %0, %1" : "+v"(X4), "+v"(Y4));

    union { unsigned int u[4]; bf16x8 v; } P0, P1;
    P0.u[0] = X1; P0.u[1] = X2; P0.u[2] = Y1; P0.u[3] = Y2;
    P1.u[0] = X3; P1.u[1] = X4; P1.u[2] = Y3; P1.u[3] = Y4;

    // O^T[d][q] += V^T . P^T
    o0 = MFMA32(v00, P0.v, o0);
    o0 = MFMA32(v01, P1.v, o0);
    o1 = MFMA32(v10, P0.v, o1);
    o1 = MFMA32(v11, P1.v, o1);

    kf0 = nf0; kf1 = nf1; kf2 = nf2; kf3 = nf3;
    hb0 = nh0; hb1 = nh1; hb2 = nh2; hb3 = nh3;
  }

  // ---- split-softmax merge via LDS ----
  // element o0[4g+e] is d = 8g+4hi+e; o1 same +32
  {
    float* orow = &osh[w][c31 * 65];
#pragma unroll
    for (int g = 0; g < 4; g++)
#pragma unroll
      for (int e = 0; e < 4; e++) {
        orow[8 * g + 4 * hi + e]      = o0[4 * g + e];
        orow[32 + 8 * g + 4 * hi + e] = o1[4 * g + e];
      }
    if (hi == 0) { msh[w][c31] = m; lsh[w][c31] = l; }
  }
  __syncthreads();

  // each wave merges 2 of the 8 d-groups for all 32 q
  float wgt[4];
  {
    float M = fmaxf(fmaxf(msh[0][c31], msh[1][c31]),
                    fmaxf(msh[2][c31], msh[3][c31]));
#pragma unroll
    for (int u = 0; u < 4; u++) wgt[u] = exp2f(msh[u][c31] - M);
  }
  float L = lsh[0][c31] * wgt[0] + lsh[1][c31] * wgt[1] +
            lsh[2][c31] * wgt[2] + lsh[3][c31] * wgt[3];
  const float inv = 1.0f / L;
  unsigned short* ob = O + (size_t)(qb + c31) * DM + head * DH;
#pragma unroll
  for (int gg = 0; gg < 2; gg++) {
    const int G = 2 * w + gg;
    const int dbase = 8 * (G & 3) + 4 * hi + 32 * (G >> 2);
    us4 pk;
#pragma unroll
    for (int e = 0; e < 4; e++) {
      float acc = osh[0][c31 * 65 + dbase + e] * wgt[0] +
                  osh[1][c31 * 65 + dbase + e] * wgt[1] +
                  osh[2][c31 * 65 + dbase + e] * wgt[2] +
                  osh[3][c31 * 65 + dbase + e] * wgt[3];
      pk[e] = f2bf(acc * inv);
    }
    *(us4*)(ob + dbase) = pk;
  }
}

extern "C" void kernel_launch(void* const* d_in, const int* in_sizes, int n_in,
                              void* d_out, int out_size, void* d_ws, size_t ws_size,
                              hipStream_t stream) {
  const float* x  = (const float*)d_in[0];
  const float* h  = (const float*)d_in[1];
  const float* Wq = (const float*)d_in[2];
  const float* bq = (const float*)d_in[3];
  const float* Wk = (const float*)d_in[4];
  const float* bk = (const float*)d_in[5];
  const float* Wv = (const float*)d_in[6];
  const float* bv = (const float*)d_in[7];
  const float* Wo = (const float*)d_in[8];
  const float* bo = (const float*)d_in[9];
  float* out = (float*)d_out;

  char* ws = (char*)d_ws;
  const size_t MB = 1 << 20;
  unsigned short* xb    = (unsigned short*)(ws + 0 * MB);   // 8 MB
  unsigned short* wqkvb = (unsigned short*)(ws + 8 * MB);   // 6 MB
  unsigned short* wob   = (unsigned short*)(ws + 14 * MB);  // 2 MB
  unsigned short* Qb    = (unsigned short*)(ws + 16 * MB);  // 8 MB
  unsigned short* Kb    = (unsigned short*)(ws + 24 * MB);  // 8 MB
  unsigned short* Vtb   = (unsigned short*)(ws + 32 * MB);  // 8 MB
  unsigned short* AOb   = (unsigned short*)(ws + 40 * MB);  // 8 MB
  float*          hperm = (float*)(ws + 48 * MB);           // 16 KB

  cvt_kernel<<<4096, 256, 0, stream>>>(x,  xb, (NTOK * DM) / 4);
  cvt_kernel<<<1024, 256, 0, stream>>>(Wq, wqkvb,               (DM * DM) / 4);
  cvt_kernel<<<1024, 256, 0, stream>>>(Wk, wqkvb + DM * DM,     (DM * DM) / 4);
  cvt_kernel<<<1024, 256, 0, stream>>>(Wv, wqkvb + 2 * DM * DM, (DM * DM) / 4);
  cvt_kernel<<<1024, 256, 0, stream>>>(Wo, wob,                 (DM * DM) / 4);
  hprep_kernel<<<16, 256, 0, stream>>>(h, hperm);

  gemm_qkv<<<dim3(24, 32), 256, 0, stream>>>(xb, wqkvb, bq, bk, bv, Qb, Kb, Vtb);

  attn_kernel<<<dim3(NTOK / 32, NH), 256, 0, stream>>>(Qb, Kb, Vtb, hperm, AOb);

  gemm_out<<<dim3(DM / 128, NTOK / 128), 256, 0, stream>>>(AOb, wob, bo, x, out);
}

// Round 4
// 343.017 us; speedup vs baseline: 1.3278x; 1.3278x over previous
//
#include <hip/hip_runtime.h>
#include <hip/hip_bf16.h>
#include <stdint.h>

#define NTOK 4096
#define DM   1024
#define NH   16
#define DH   64
#define SCL  0.1803368801111129f   /* 0.125 * log2(e) */
#define LOG2E 1.4426950408889634f

typedef __attribute__((ext_vector_type(8)))  short bf16x8;
typedef __attribute__((ext_vector_type(4)))  float f32x4;
typedef __attribute__((ext_vector_type(16))) float f32x16;
typedef __attribute__((ext_vector_type(4)))  unsigned short us4;

__device__ inline unsigned short f2bf(float f) {
  union { float f; unsigned int u; } a;
  a.f = f;
  unsigned int u = a.u;
  u += 0x7fffu + ((u >> 16) & 1u);
  return (unsigned short)(u >> 16);
}

__device__ inline unsigned int cvtpk_bf16(float lo, float hi) {
  unsigned int r;
  asm("v_cvt_pk_bf16_f32 %0, %1, %2" : "=v"(r) : "v"(lo), "v"(hi));
  return r;
}

__device__ inline void gload_lds16(const void* gsrc, void* ldst) {
  __builtin_amdgcn_global_load_lds(
      (const __attribute__((address_space(1))) void*)(uintptr_t)gsrc,
      (__attribute__((address_space(3))) void*)(unsigned int)(uintptr_t)ldst,
      16, 0, 0);
}

// ---------------- f32 -> bf16 conversion ----------------
__global__ void cvt_kernel(const float* __restrict__ in,
                           unsigned short* __restrict__ out, int n4) {
  int i = blockIdx.x * 256 + threadIdx.x;
  if (i < n4) {
    float4 v = ((const float4*)in)[i];
    us4 o;
    o[0] = f2bf(v.x); o[1] = f2bf(v.y); o[2] = f2bf(v.z); o[3] = f2bf(v.w);
    ((us4*)out)[i] = o;
  }
}

// ---------------- h permute: hperm[t*32 + hi*16 + r] = log2e*h[key] --------
__global__ void hprep_kernel(const float* __restrict__ h,
                             float* __restrict__ hperm) {
  int i = blockIdx.x * 256 + threadIdx.x;      // 0..4095
  int r  = i & 15;
  int hi = (i >> 4) & 1;
  int t  = i >> 5;
  int key = t * 32 + (r & 3) + 8 * (r >> 2) + 4 * hi;
  hperm[i] = LOG2E * h[key];                   // GAMMA = 1
}

// ---------------- fused QKV GEMM: A[4096][1024] x Wpack[3072][1024]^T ------
__global__ __launch_bounds__(256)
void gemm_qkv(const unsigned short* __restrict__ A,
              const unsigned short* __restrict__ B,
              const float* __restrict__ bq, const float* __restrict__ bk,
              const float* __restrict__ bv,
              unsigned short* __restrict__ Qb, unsigned short* __restrict__ Kb,
              unsigned short* __restrict__ Vt)
{
  const int tid  = threadIdx.x;
  const int wid  = tid >> 6;
  const int lane = tid & 63;
  const int bn = blockIdx.x * 128;
  const int bm = blockIdx.y * 128;
  const int wr = wid >> 1;
  const int wc = wid & 1;

  __shared__ __align__(16) unsigned short As[128 * 32];
  __shared__ __align__(16) unsigned short Bs[128 * 32];

  f32x4 acc[4][4];
#pragma unroll
  for (int i = 0; i < 4; i++)
#pragma unroll
    for (int j = 0; j < 4; j++) acc[i][j] = f32x4{0.f, 0.f, 0.f, 0.f};

  const int fr = lane & 15;
  const int fk = (lane >> 4) * 8;
  const int srow = lane >> 2;
  const int scol = (lane & 3) * 8;

  for (int k0 = 0; k0 < DM; k0 += 32) {
#pragma unroll
    for (int c = 0; c < 2; ++c) {
      const int chunk = wid * 2 + c;
      gload_lds16(A + (size_t)(bm + chunk * 16 + srow) * DM + k0 + scol,
                  &As[chunk * 512]);
      gload_lds16(B + (size_t)(bn + chunk * 16 + srow) * DM + k0 + scol,
                  &Bs[chunk * 512]);
    }
    __syncthreads();
    bf16x8 af[4], bfr[4];
#pragma unroll
    for (int i = 0; i < 4; i++)
      af[i] = *(const bf16x8*)&As[(wr * 64 + i * 16 + fr) * 32 + fk];
#pragma unroll
    for (int j = 0; j < 4; j++)
      bfr[j] = *(const bf16x8*)&Bs[(wc * 64 + j * 16 + fr) * 32 + fk];
#pragma unroll
    for (int i = 0; i < 4; i++)
#pragma unroll
      for (int j = 0; j < 4; j++)
        acc[i][j] = __builtin_amdgcn_mfma_f32_16x16x32_bf16(af[i], bfr[j],
                                                            acc[i][j], 0, 0, 0);
    __syncthreads();
  }

  const int fq = lane >> 4;
  const int region = bn >> 10;                       // 0=Q 1=K 2=V
  const float* bias = (region == 0) ? bq : (region == 1) ? bk : bv;
  unsigned short* outp = (region == 0) ? Qb : Kb;
#pragma unroll
  for (int j = 0; j < 4; j++) {
    const int col = bn + wc * 64 + j * 16 + fr;
    const int cl  = col & 1023;
    const float bvx = bias[cl];
#pragma unroll
    for (int i = 0; i < 4; i++) {
      const int row0 = bm + wr * 64 + i * 16 + fq * 4;
      if (region < 2) {
#pragma unroll
        for (int r = 0; r < 4; r++)
          outp[(size_t)(row0 + r) * DM + cl] = f2bf(acc[i][j][r] + bvx);
      } else {
        us4 pk;
#pragma unroll
        for (int r = 0; r < 4; r++) pk[r] = f2bf(acc[i][j][r] + bvx);
        *(us4*)&Vt[(size_t)cl * NTOK + row0] = pk;
      }
    }
  }
}

// ---------------- final GEMM: out = AO x Wo^T + bo + x  (f32 out) ----------
__global__ __launch_bounds__(256)
void gemm_out(const unsigned short* __restrict__ A,
              const unsigned short* __restrict__ B,
              const float* __restrict__ bias,
              const float* __restrict__ resid,
              float* __restrict__ Cf)
{
  const int tid  = threadIdx.x;
  const int wid  = tid >> 6;
  const int lane = tid & 63;
  const int bn = blockIdx.x * 128;
  const int bm = blockIdx.y * 128;
  const int wr = wid >> 1;
  const int wc = wid & 1;

  __shared__ __align__(16) unsigned short As[128 * 32];
  __shared__ __align__(16) unsigned short Bs[128 * 32];

  f32x4 acc[4][4];
#pragma unroll
  for (int i = 0; i < 4; i++)
#pragma unroll
    for (int j = 0; j < 4; j++) acc[i][j] = f32x4{0.f, 0.f, 0.f, 0.f};

  const int fr = lane & 15;
  const int fk = (lane >> 4) * 8;
  const int srow = lane >> 2;
  const int scol = (lane & 3) * 8;

  for (int k0 = 0; k0 < DM; k0 += 32) {
#pragma unroll
    for (int c = 0; c < 2; ++c) {
      const int chunk = wid * 2 + c;
      gload_lds16(A + (size_t)(bm + chunk * 16 + srow) * DM + k0 + scol,
                  &As[chunk * 512]);
      gload_lds16(B + (size_t)(bn + chunk * 16 + srow) * DM + k0 + scol,
                  &Bs[chunk * 512]);
    }
    __syncthreads();
    bf16x8 af[4], bfr[4];
#pragma unroll
    for (int i = 0; i < 4; i++)
      af[i] = *(const bf16x8*)&As[(wr * 64 + i * 16 + fr) * 32 + fk];
#pragma unroll
    for (int j = 0; j < 4; j++)
      bfr[j] = *(const bf16x8*)&Bs[(wc * 64 + j * 16 + fr) * 32 + fk];
#pragma unroll
    for (int i = 0; i < 4; i++)
#pragma unroll
      for (int j = 0; j < 4; j++)
        acc[i][j] = __builtin_amdgcn_mfma_f32_16x16x32_bf16(af[i], bfr[j],
                                                            acc[i][j], 0, 0, 0);
    __syncthreads();
  }

  const int fq = lane >> 4;
#pragma unroll
  for (int j = 0; j < 4; j++) {
    const int col = bn + wc * 64 + j * 16 + fr;
    const float bvx = bias[col];
#pragma unroll
    for (int i = 0; i < 4; i++) {
      const int row0 = bm + wr * 64 + i * 16 + fq * 4;
#pragma unroll
      for (int r = 0; r < 4; r++) {
        const size_t idx = (size_t)(row0 + r) * DM + col;
        Cf[idx] = acc[i][j][r] + bvx + resid[idx];
      }
    }
  }
}

// ---------------- attention: swapped-QK^T 32x32, in-register softmax -------
// 4 waves/block each own a 1024-key quarter of the SAME 32 q rows;
// split-softmax merge through LDS at the end. No software prefetch (register
// budget: fit 128 VGPR for 4 waves/SIMD without spill — round-3 spilled).
#define MFMA32(a, b, c) __builtin_amdgcn_mfma_f32_32x32x16_bf16(a, b, c, 0, 0, 0)

__global__ __launch_bounds__(256, 4)
void attn_kernel(const unsigned short* __restrict__ Q,
                 const unsigned short* __restrict__ K,
                 const unsigned short* __restrict__ Vt,
                 const float* __restrict__ hperm,
                 unsigned short* __restrict__ O)
{
  // XCD swizzle: 2048 blocks, 8 XCDs -> 256 consecutive wgids per XCD
  // = 2 full heads per XCD (K+V = 2 MB, fits 4 MB L2).
  const int wgid = (blockIdx.x & 7) * 256 + (blockIdx.x >> 3);
  const int head = wgid >> 7;
  const int qb   = (wgid & 127) * 32;
  const int tid  = threadIdx.x;
  const int w    = tid >> 6;
  const int lane = tid & 63;
  const int c31  = lane & 31;
  const int hi   = lane >> 5;

  __shared__ float osh[4][32 * 65];   // pad-65: conflict-free scalar access
  __shared__ float msh[4][32];
  __shared__ float lsh[4][32];

  // Q fragment (B-operand): lane holds Q[qb+c31][16c + 8*hi + j]
  const unsigned short* qp = Q + (size_t)(qb + c31) * DM + head * DH + hi * 8;
  const bf16x8 qf0 = *(const bf16x8*)(qp);
  const bf16x8 qf1 = *(const bf16x8*)(qp + 16);
  const bf16x8 qf2 = *(const bf16x8*)(qp + 32);
  const bf16x8 qf3 = *(const bf16x8*)(qp + 48);

  const int k0 = w * (NTOK / 4);                 // this wave's key range base
  const unsigned short* kp = K + (size_t)(k0 + c31) * DM + head * DH + hi * 8;
  const unsigned short* vp = Vt + (size_t)(head * DH + c31) * NTOK + k0 + hi * 8;
  const float* hp = hperm + k0 + hi * 16;

  f32x16 o0, o1;
#pragma unroll
  for (int i = 0; i < 16; i++) { o0[i] = 0.f; o1[i] = 0.f; }
  float m = -3.0e38f, l = 0.f;

  const int NT = NTOK / 4 / 32;                  // 32 tiles per wave
  for (int t = 0; t < NT; ++t) {
    const unsigned short* kb = kp + (size_t)t * 32 * DM;
    const bf16x8 kf0 = *(const bf16x8*)(kb);
    const bf16x8 kf1 = *(const bf16x8*)(kb + 16);
    const bf16x8 kf2 = *(const bf16x8*)(kb + 32);
    const bf16x8 kf3 = *(const bf16x8*)(kb + 48);
    const unsigned short* vb = vp + t * 32;
    const bf16x8 v00 = *(const bf16x8*)(vb);
    const bf16x8 v01 = *(const bf16x8*)(vb + 16);
    const bf16x8 v10 = *(const bf16x8*)(vb + (size_t)32 * NTOK);
    const bf16x8 v11 = *(const bf16x8*)(vb + (size_t)32 * NTOK + 16);

    // S^T[key][q] = K . Q^T
    f32x16 s;
#pragma unroll
    for (int i = 0; i < 16; i++) s[i] = 0.f;
    __builtin_amdgcn_s_setprio(1);
    s = MFMA32(kf0, qf0, s);
    s = MFMA32(kf1, qf1, s);
    s = MFMA32(kf2, qf2, s);
    s = MFMA32(kf3, qf3, s);
    __builtin_amdgcn_s_setprio(0);

    const float* hb = hp + t * 32;
    const float4 hb0 = *(const float4*)(hb + 0);
    const float4 hb1 = *(const float4*)(hb + 4);
    const float4 hb2 = *(const float4*)(hb + 8);
    const float4 hb3 = *(const float4*)(hb + 12);

    // logits in log2 domain: L = s*SCL - hb
    float Lv[16];
    Lv[0]  = fmaf(s[0],  SCL, -hb0.x); Lv[1]  = fmaf(s[1],  SCL, -hb0.y);
    Lv[2]  = fmaf(s[2],  SCL, -hb0.z); Lv[3]  = fmaf(s[3],  SCL, -hb0.w);
    Lv[4]  = fmaf(s[4],  SCL, -hb1.x); Lv[5]  = fmaf(s[5],  SCL, -hb1.y);
    Lv[6]  = fmaf(s[6],  SCL, -hb1.z); Lv[7]  = fmaf(s[7],  SCL, -hb1.w);
    Lv[8]  = fmaf(s[8],  SCL, -hb2.x); Lv[9]  = fmaf(s[9],  SCL, -hb2.y);
    Lv[10] = fmaf(s[10], SCL, -hb2.z); Lv[11] = fmaf(s[11], SCL, -hb2.w);
    Lv[12] = fmaf(s[12], SCL, -hb3.x); Lv[13] = fmaf(s[13], SCL, -hb3.y);
    Lv[14] = fmaf(s[14], SCL, -hb3.z); Lv[15] = fmaf(s[15], SCL, -hb3.w);

    float pm = fmaxf(fmaxf(fmaxf(Lv[0], Lv[1]), fmaxf(Lv[2], Lv[3])),
                     fmaxf(fmaxf(Lv[4], Lv[5]), fmaxf(Lv[6], Lv[7])));
    pm = fmaxf(pm, fmaxf(fmaxf(fmaxf(Lv[8], Lv[9]), fmaxf(Lv[10], Lv[11])),
                         fmaxf(fmaxf(Lv[12], Lv[13]), fmaxf(Lv[14], Lv[15]))));
    pm = fmaxf(pm, __shfl_xor(pm, 32, 64));

    // defer-max (T13)
    if (!__all(pm <= m + 8.0f)) {
      const float mn = fmaxf(m, pm);
      const float al = exp2f(m - mn);
      m = mn;
      l *= al;
#pragma unroll
      for (int i = 0; i < 16; i++) { o0[i] *= al; o1[i] *= al; }
    }

    float ps[16];
#pragma unroll
    for (int r = 0; r < 16; r++) ps[r] = exp2f(Lv[r] - m);
    float rs = (((ps[0] + ps[1]) + (ps[2] + ps[3])) +
                ((ps[4] + ps[5]) + (ps[6] + ps[7]))) +
               (((ps[8] + ps[9]) + (ps[10] + ps[11])) +
                ((ps[12] + ps[13]) + (ps[14] + ps[15])));
    rs += __shfl_xor(rs, 32, 64);
    l += rs;

    // pack P^T into B-fragments via cvt_pk + permlane32_swap (T12)
    unsigned int X1 = cvtpk_bf16(ps[0],  ps[1]);
    unsigned int X2 = cvtpk_bf16(ps[2],  ps[3]);
    unsigned int Y1 = cvtpk_bf16(ps[4],  ps[5]);
    unsigned int Y2 = cvtpk_bf16(ps[6],  ps[7]);
    asm("v_permlane32_swap_b32 %0, %1" : "+v"(X1), "+v"(Y1));
    asm("v_permlane32_swap_b32 %0, %1" : "+v"(X2), "+v"(Y2));
    unsigned int X3 = cvtpk_bf16(ps[8],  ps[9]);
    unsigned int X4 = cvtpk_bf16(ps[10], ps[11]);
    unsigned int Y3 = cvtpk_bf16(ps[12], ps[13]);
    unsigned int Y4 = cvtpk_bf16(ps[14], ps[15]);
    asm("v_permlane32_swap_b32 %0, %1" : "+v"(X3), "+v"(Y3));
    asm("v_permlane32_swap_b32 %0, %1" : "+v"(X4), "+v"(Y4));

    union { unsigned int u[4]; bf16x8 v; } P0, P1;
    P0.u[0] = X1; P0.u[1] = X2; P0.u[2] = Y1; P0.u[3] = Y2;
    P1.u[0] = X3; P1.u[1] = X4; P1.u[2] = Y3; P1.u[3] = Y4;

    // O^T[d][q] += V^T . P^T
    __builtin_amdgcn_s_setprio(1);
    o0 = MFMA32(v00, P0.v, o0);
    o0 = MFMA32(v01, P1.v, o0);
    o1 = MFMA32(v10, P0.v, o1);
    o1 = MFMA32(v11, P1.v, o1);
    __builtin_amdgcn_s_setprio(0);
  }

  // ---- split-softmax merge via LDS ----
  // element o0[4g+e] is d = 8g+4hi+e; o1 same +32
  {
    float* orow = &osh[w][c31 * 65];
#pragma unroll
    for (int g = 0; g < 4; g++)
#pragma unroll
      for (int e = 0; e < 4; e++) {
        orow[8 * g + 4 * hi + e]      = o0[4 * g + e];
        orow[32 + 8 * g + 4 * hi + e] = o1[4 * g + e];
      }
    if (hi == 0) { msh[w][c31] = m; lsh[w][c31] = l; }
  }
  __syncthreads();

  // each wave merges 2 of the 8 d-groups for all 32 q
  float wgt[4];
  {
    float M = fmaxf(fmaxf(msh[0][c31], msh[1][c31]),
                    fmaxf(msh[2][c31], msh[3][c31]));
#pragma unroll
    for (int u = 0; u < 4; u++) wgt[u] = exp2f(msh[u][c31] - M);
  }
  float L = lsh[0][c31] * wgt[0] + lsh[1][c31] * wgt[1] +
            lsh[2][c31] * wgt[2] + lsh[3][c31] * wgt[3];
  const float inv = 1.0f / L;
  unsigned short* ob = O + (size_t)(qb + c31) * DM + head * DH;
#pragma unroll
  for (int gg = 0; gg < 2; gg++) {
    const int G = 2 * w + gg;
    const int dbase = 8 * (G & 3) + 4 * hi + 32 * (G >> 2);
    us4 pk;
#pragma unroll
    for (int e = 0; e < 4; e++) {
      float acc = osh[0][c31 * 65 + dbase + e] * wgt[0] +
                  osh[1][c31 * 65 + dbase + e] * wgt[1] +
                  osh[2][c31 * 65 + dbase + e] * wgt[2] +
                  osh[3][c31 * 65 + dbase + e] * wgt[3];
      pk[e] = f2bf(acc * inv);
    }
    *(us4*)(ob + dbase) = pk;
  }
}

extern "C" void kernel_launch(void* const* d_in, const int* in_sizes, int n_in,
                              void* d_out, int out_size, void* d_ws, size_t ws_size,
                              hipStream_t stream) {
  const float* x  = (const float*)d_in[0];
  const float* h  = (const float*)d_in[1];
  const float* Wq = (const float*)d_in[2];
  const float* bq = (const float*)d_in[3];
  const float* Wk = (const float*)d_in[4];
  const float* bk = (const float*)d_in[5];
  const float* Wv = (const float*)d_in[6];
  const float* bv = (const float*)d_in[7];
  const float* Wo = (const float*)d_in[8];
  const float* bo = (const float*)d_in[9];
  float* out = (float*)d_out;

  char* ws = (char*)d_ws;
  const size_t MB = 1 << 20;
  unsigned short* xb    = (unsigned short*)(ws + 0 * MB);   // 8 MB
  unsigned short* wqkvb = (unsigned short*)(ws + 8 * MB);   // 6 MB
  unsigned short* wob   = (unsigned short*)(ws + 14 * MB);  // 2 MB
  unsigned short* Qb    = (unsigned short*)(ws + 16 * MB);  // 8 MB
  unsigned short* Kb    = (unsigned short*)(ws + 24 * MB);  // 8 MB
  unsigned short* Vtb   = (unsigned short*)(ws + 32 * MB);  // 8 MB
  unsigned short* AOb   = (unsigned short*)(ws + 40 * MB);  // 8 MB
  float*          hperm = (float*)(ws + 48 * MB);           // 16 KB

  cvt_kernel<<<4096, 256, 0, stream>>>(x,  xb, (NTOK * DM) / 4);
  cvt_kernel<<<1024, 256, 0, stream>>>(Wq, wqkvb,               (DM * DM) / 4);
  cvt_kernel<<<1024, 256, 0, stream>>>(Wk, wqkvb + DM * DM,     (DM * DM) / 4);
  cvt_kernel<<<1024, 256, 0, stream>>>(Wv, wqkvb + 2 * DM * DM, (DM * DM) / 4);
  cvt_kernel<<<1024, 256, 0, stream>>>(Wo, wob,                 (DM * DM) / 4);
  hprep_kernel<<<16, 256, 0, stream>>>(h, hperm);

  gemm_qkv<<<dim3(24, 32), 256, 0, stream>>>(xb, wqkvb, bq, bk, bv, Qb, Kb, Vtb);

  attn_kernel<<<dim3(2048), 256, 0, stream>>>(Qb, Kb, Vtb, hperm, AOb);

  gemm_out<<<dim3(DM / 128, NTOK / 128), 256, 0, stream>>>(AOb, wob, bo, x, out);
}

// Round 5
// 204.867 us; speedup vs baseline: 2.2232x; 1.6743x over previous
//
#include <hip/hip_runtime.h>
#include <hip/hip_bf16.h>
#include <stdint.h>

#define NTOK 4096
#define DM   1024
#define NH   16
#define DH   64
#define SCL  0.1803368801111129f   /* 0.125 * log2(e) */
#define LOG2E 1.4426950408889634f

typedef __attribute__((ext_vector_type(8)))  short bf16x8;
typedef __attribute__((ext_vector_type(4)))  float f32x4;
typedef __attribute__((ext_vector_type(16))) float f32x16;
typedef __attribute__((ext_vector_type(4)))  unsigned short us4;

__device__ inline unsigned short f2bf(float f) {
  union { float f; unsigned int u; } a;
  a.f = f;
  unsigned int u = a.u;
  u += 0x7fffu + ((u >> 16) & 1u);
  return (unsigned short)(u >> 16);
}

__device__ inline unsigned int cvtpk_bf16(float lo, float hi) {
  unsigned int r;
  asm("v_cvt_pk_bf16_f32 %0, %1, %2" : "=v"(r) : "v"(lo), "v"(hi));
  return r;
}

__device__ inline void gload_lds16(const void* gsrc, void* ldst) {
  __builtin_amdgcn_global_load_lds(
      (const __attribute__((address_space(1))) void*)(uintptr_t)gsrc,
      (__attribute__((address_space(3))) void*)(unsigned int)(uintptr_t)ldst,
      16, 0, 0);
}

// ---------------- f32 -> bf16 conversion ----------------
__global__ void cvt_kernel(const float* __restrict__ in,
                           unsigned short* __restrict__ out, int n4) {
  int i = blockIdx.x * 256 + threadIdx.x;
  if (i < n4) {
    float4 v = ((const float4*)in)[i];
    us4 o;
    o[0] = f2bf(v.x); o[1] = f2bf(v.y); o[2] = f2bf(v.z); o[3] = f2bf(v.w);
    ((us4*)out)[i] = o;
  }
}

// ---- h permute: hperm[t*32 + hi*16 + r] = -log2e*h[key]  (MFMA C-init) ----
__global__ void hprep_kernel(const float* __restrict__ h,
                             float* __restrict__ hperm) {
  int i = blockIdx.x * 256 + threadIdx.x;      // 0..4095
  int r  = i & 15;
  int hi = (i >> 4) & 1;
  int t  = i >> 5;
  int key = t * 32 + (r & 3) + 8 * (r >> 2) + 4 * hi;
  hperm[i] = -LOG2E * h[key];                  // GAMMA = 1
}

// ---------------- fused QKV GEMM: A[4096][1024] x Wpack[3072][1024]^T ------
// Q region pre-scaled by SCL so attn logits come out in log2 domain.
__global__ __launch_bounds__(256)
void gemm_qkv(const unsigned short* __restrict__ A,
              const unsigned short* __restrict__ B,
              const float* __restrict__ bq, const float* __restrict__ bk,
              const float* __restrict__ bv,
              unsigned short* __restrict__ Qb, unsigned short* __restrict__ Kb,
              unsigned short* __restrict__ Vt)
{
  const int tid  = threadIdx.x;
  const int wid  = tid >> 6;
  const int lane = tid & 63;
  const int bn = blockIdx.x * 128;
  const int bm = blockIdx.y * 128;
  const int wr = wid >> 1;
  const int wc = wid & 1;

  __shared__ __align__(16) unsigned short As[128 * 32];
  __shared__ __align__(16) unsigned short Bs[128 * 32];

  f32x4 acc[4][4];
#pragma unroll
  for (int i = 0; i < 4; i++)
#pragma unroll
    for (int j = 0; j < 4; j++) acc[i][j] = f32x4{0.f, 0.f, 0.f, 0.f};

  const int fr = lane & 15;
  const int fk = (lane >> 4) * 8;
  const int srow = lane >> 2;
  const int scol = (lane & 3) * 8;

  for (int k0 = 0; k0 < DM; k0 += 32) {
#pragma unroll
    for (int c = 0; c < 2; ++c) {
      const int chunk = wid * 2 + c;
      gload_lds16(A + (size_t)(bm + chunk * 16 + srow) * DM + k0 + scol,
                  &As[chunk * 512]);
      gload_lds16(B + (size_t)(bn + chunk * 16 + srow) * DM + k0 + scol,
                  &Bs[chunk * 512]);
    }
    __syncthreads();
    bf16x8 af[4], bfr[4];
#pragma unroll
    for (int i = 0; i < 4; i++)
      af[i] = *(const bf16x8*)&As[(wr * 64 + i * 16 + fr) * 32 + fk];
#pragma unroll
    for (int j = 0; j < 4; j++)
      bfr[j] = *(const bf16x8*)&Bs[(wc * 64 + j * 16 + fr) * 32 + fk];
#pragma unroll
    for (int i = 0; i < 4; i++)
#pragma unroll
      for (int j = 0; j < 4; j++)
        acc[i][j] = __builtin_amdgcn_mfma_f32_16x16x32_bf16(af[i], bfr[j],
                                                            acc[i][j], 0, 0, 0);
    __syncthreads();
  }

  const int fq = lane >> 4;
  const int region = bn >> 10;                       // 0=Q 1=K 2=V
  const float* bias = (region == 0) ? bq : (region == 1) ? bk : bv;
  const float qscale = (region == 0) ? SCL : 1.0f;
  unsigned short* outp = (region == 0) ? Qb : Kb;
#pragma unroll
  for (int j = 0; j < 4; j++) {
    const int col = bn + wc * 64 + j * 16 + fr;
    const int cl  = col & 1023;
    const float bvx = bias[cl];
#pragma unroll
    for (int i = 0; i < 4; i++) {
      const int row0 = bm + wr * 64 + i * 16 + fq * 4;
      if (region < 2) {
#pragma unroll
        for (int r = 0; r < 4; r++)
          outp[(size_t)(row0 + r) * DM + cl] = f2bf((acc[i][j][r] + bvx) * qscale);
      } else {
        us4 pk;
#pragma unroll
        for (int r = 0; r < 4; r++) pk[r] = f2bf(acc[i][j][r] + bvx);
        *(us4*)&Vt[(size_t)cl * NTOK + row0] = pk;
      }
    }
  }
}

// ---------------- final GEMM: out = AO x Wo^T + bo + x  (f32 out) ----------
__global__ __launch_bounds__(256)
void gemm_out(const unsigned short* __restrict__ A,
              const unsigned short* __restrict__ B,
              const float* __restrict__ bias,
              const float* __restrict__ resid,
              float* __restrict__ Cf)
{
  const int tid  = threadIdx.x;
  const int wid  = tid >> 6;
  const int lane = tid & 63;
  const int bn = blockIdx.x * 128;
  const int bm = blockIdx.y * 128;
  const int wr = wid >> 1;
  const int wc = wid & 1;

  __shared__ __align__(16) unsigned short As[128 * 32];
  __shared__ __align__(16) unsigned short Bs[128 * 32];

  f32x4 acc[4][4];
#pragma unroll
  for (int i = 0; i < 4; i++)
#pragma unroll
    for (int j = 0; j < 4; j++) acc[i][j] = f32x4{0.f, 0.f, 0.f, 0.f};

  const int fr = lane & 15;
  const int fk = (lane >> 4) * 8;
  const int srow = lane >> 2;
  const int scol = (lane & 3) * 8;

  for (int k0 = 0; k0 < DM; k0 += 32) {
#pragma unroll
    for (int c = 0; c < 2; ++c) {
      const int chunk = wid * 2 + c;
      gload_lds16(A + (size_t)(bm + chunk * 16 + srow) * DM + k0 + scol,
                  &As[chunk * 512]);
      gload_lds16(B + (size_t)(bn + chunk * 16 + srow) * DM + k0 + scol,
                  &Bs[chunk * 512]);
    }
    __syncthreads();
    bf16x8 af[4], bfr[4];
#pragma unroll
    for (int i = 0; i < 4; i++)
      af[i] = *(const bf16x8*)&As[(wr * 64 + i * 16 + fr) * 32 + fk];
#pragma unroll
    for (int j = 0; j < 4; j++)
      bfr[j] = *(const bf16x8*)&Bs[(wc * 64 + j * 16 + fr) * 32 + fk];
#pragma unroll
    for (int i = 0; i < 4; i++)
#pragma unroll
      for (int j = 0; j < 4; j++)
        acc[i][j] = __builtin_amdgcn_mfma_f32_16x16x32_bf16(af[i], bfr[j],
                                                            acc[i][j], 0, 0, 0);
    __syncthreads();
  }

  const int fq = lane >> 4;
#pragma unroll
  for (int j = 0; j < 4; j++) {
    const int col = bn + wc * 64 + j * 16 + fr;
    const float bvx = bias[col];
#pragma unroll
    for (int i = 0; i < 4; i++) {
      const int row0 = bm + wr * 64 + i * 16 + fq * 4;
#pragma unroll
      for (int r = 0; r < 4; r++) {
        const size_t idx = (size_t)(row0 + r) * DM + col;
        Cf[idx] = acc[i][j][r] + bvx + resid[idx];
      }
    }
  }
}

// ---------------- attention: LDS-staged shared K/V, no-max softmax ---------
// Block = 4 waves x 32q (same 4096-key stream). K/V tiles (32 keys) staged in
// LDS double-buffered via global_load_lds with SOURCE-side XOR swizzle
// (linear LDS dest, m104/m173), fragments via swizzled ds_read_b128.
// Softmax is unnormalized exp2 (logits bounded, no max needed): Q pre-scaled
// by SCL, -log2e*h loaded as MFMA C-init. One shfl at the very end.
#define MFMA32(a, b, c) __builtin_amdgcn_mfma_f32_32x32x16_bf16(a, b, c, 0, 0, 0)

__global__ __launch_bounds__(256)
void attn_kernel(const unsigned short* __restrict__ Q,
                 const unsigned short* __restrict__ K,
                 const unsigned short* __restrict__ Vt,
                 const float* __restrict__ hperm,
                 unsigned short* __restrict__ O)
{
  // 512 blocks = 8 XCDs x 64: 2 heads per XCD (K+V 4MB fits per-XCD L2)
  const int wgid = (blockIdx.x & 7) * 64 + (blockIdx.x >> 3);
  const int head = wgid >> 5;
  const int tid  = threadIdx.x;
  const int w    = tid >> 6;
  const int lane = tid & 63;
  const int c31  = lane & 31;
  const int hi   = lane >> 5;
  const int qb   = (wgid & 31) * 128 + w * 32;

  __shared__ __align__(16) unsigned short Ks[2][2048];  // [32 keys][64 d] swz
  __shared__ __align__(16) unsigned short Vs[2][2048];  // [64 d][32 keys] swz

  // staging source mapping (pre-swizzled so linear LDS dest = swizzled tile)
  const int krow = lane >> 3;                    // 0..7 within wave's 8 rows
  const int kchk = (lane & 7) ^ krow;            // logical 16B chunk 0..7
  const int vd   = lane >> 2;                    // 0..15 within wave's 16 d
  const int vchk = (lane & 3) ^ (vd & 3);        // logical 16B chunk 0..3
  const unsigned short* kg =
      K + (size_t)(8 * w + krow) * DM + head * DH + kchk * 8;
  const unsigned short* vg =
      Vt + (size_t)(head * DH + 16 * w + vd) * NTOK + vchk * 8;

  // fragment read offsets (swizzled)
  int koff[4], voff[2][2];
#pragma unroll
  for (int f = 0; f < 4; f++)
    koff[f] = c31 * 64 + ((f * 2 + hi) ^ (c31 & 7)) * 8;
#pragma unroll
  for (int db = 0; db < 2; db++)
#pragma unroll
    for (int ko = 0; ko < 2; ko++)
      voff[db][ko] = (db * 32 + c31) * 32 + ((ko * 2 + hi) ^ (c31 & 3)) * 8;

  // Q fragments (pre-scaled by SCL in GEMM)
  const unsigned short* qp = Q + (size_t)(qb + c31) * DM + head * DH + hi * 8;
  const bf16x8 qf0 = *(const bf16x8*)(qp);
  const bf16x8 qf1 = *(const bf16x8*)(qp + 16);
  const bf16x8 qf2 = *(const bf16x8*)(qp + 32);
  const bf16x8 qf3 = *(const bf16x8*)(qp + 48);

  f32x16 o0, o1;
#pragma unroll
  for (int i = 0; i < 16; i++) { o0[i] = 0.f; o1[i] = 0.f; }
  float l = 0.f;

  // prologue: stage tile 0 into buffer 0 (each wave stages its quarter)
  gload_lds16(kg, &Ks[0][w * 512]);
  gload_lds16(vg, &Vs[0][w * 512]);
  __syncthreads();

  int cur = 0;
  const int NT = NTOK / 32;                      // 128 tiles
  for (int t = 0; t < NT; ++t) {
    const int kt = t * 32;
    if (t + 1 < NT) {                            // stage next tile (async)
      gload_lds16(kg + (size_t)(kt + 32) * DM, &Ks[cur ^ 1][w * 512]);
      gload_lds16(vg + (kt + 32), &Vs[cur ^ 1][w * 512]);
    }

    // bias as accumulator init: s = -log2e*h (permuted layout)
    const float* hp = hperm + kt + hi * 16;
    const float4 b0 = *(const float4*)(hp + 0);
    const float4 b1 = *(const float4*)(hp + 4);
    const float4 b2 = *(const float4*)(hp + 8);
    const float4 b3 = *(const float4*)(hp + 12);
    f32x16 s;
    s[0]  = b0.x; s[1]  = b0.y; s[2]  = b0.z; s[3]  = b0.w;
    s[4]  = b1.x; s[5]  = b1.y; s[6]  = b1.z; s[7]  = b1.w;
    s[8]  = b2.x; s[9]  = b2.y; s[10] = b2.z; s[11] = b2.w;
    s[12] = b3.x; s[13] = b3.y; s[14] = b3.z; s[15] = b3.w;

    const bf16x8 kf0 = *(const bf16x8*)&Ks[cur][koff[0]];
    const bf16x8 kf1 = *(const bf16x8*)&Ks[cur][koff[1]];
    const bf16x8 kf2 = *(const bf16x8*)&Ks[cur][koff[2]];
    const bf16x8 kf3 = *(const bf16x8*)&Ks[cur][koff[3]];
    const bf16x8 v00 = *(const bf16x8*)&Vs[cur][voff[0][0]];
    const bf16x8 v01 = *(const bf16x8*)&Vs[cur][voff[0][1]];
    const bf16x8 v10 = *(const bf16x8*)&Vs[cur][voff[1][0]];
    const bf16x8 v11 = *(const bf16x8*)&Vs[cur][voff[1][1]];

    // S^T[key][q] = K . Q^T  (log2-domain logits, bias pre-added)
    s = MFMA32(kf0, qf0, s);
    s = MFMA32(kf1, qf1, s);
    s = MFMA32(kf2, qf2, s);
    s = MFMA32(kf3, qf3, s);

    // unnormalized softmax: p = 2^s
    float ps[16];
#pragma unroll
    for (int r = 0; r < 16; r++) ps[r] = __builtin_amdgcn_exp2f(s[r]);
    const float rs = (((ps[0] + ps[1]) + (ps[2] + ps[3])) +
                      ((ps[4] + ps[5]) + (ps[6] + ps[7]))) +
                     (((ps[8] + ps[9]) + (ps[10] + ps[11])) +
                      ((ps[12] + ps[13]) + (ps[14] + ps[15])));
    l += rs;

    // pack P^T into B-fragments via cvt_pk + permlane32_swap (T12)
    unsigned int X1 = cvtpk_bf16(ps[0],  ps[1]);
    unsigned int X2 = cvtpk_bf16(ps[2],  ps[3]);
    unsigned int Y1 = cvtpk_bf16(ps[4],  ps[5]);
    unsigned int Y2 = cvtpk_bf16(ps[6],  ps[7]);
    asm("v_permlane32_swap_b32 %0, %1" : "+v"(X1), "+v"(Y1));
    asm("v_permlane32_swap_b32 %0, %1" : "+v"(X2), "+v"(Y2));
    unsigned int X3 = cvtpk_bf16(ps[8],  ps[9]);
    unsigned int X4 = cvtpk_bf16(ps[10], ps[11]);
    unsigned int Y3 = cvtpk_bf16(ps[12], ps[13]);
    unsigned int Y4 = cvtpk_bf16(ps[14], ps[15]);
    asm("v_permlane32_swap_b32 %0, %1" : "+v"(X3), "+v"(Y3));
    asm("v_permlane32_swap_b32 %0, %1" : "+v"(X4), "+v"(Y4));

    union { unsigned int u[4]; bf16x8 v; } P0, P1;
    P0.u[0] = X1; P0.u[1] = X2; P0.u[2] = Y1; P0.u[3] = Y2;
    P1.u[0] = X3; P1.u[1] = X4; P1.u[2] = Y3; P1.u[3] = Y4;

    // O^T[d][q] += V^T . P^T
    o0 = MFMA32(v00, P0.v, o0);
    o0 = MFMA32(v01, P1.v, o0);
    o1 = MFMA32(v10, P0.v, o1);
    o1 = MFMA32(v11, P1.v, o1);

    __syncthreads();   // staged tile complete (vmcnt0) + all reads done
    cur ^= 1;
  }

  // cross-half denominator merge (each half summed disjoint key sets)
  l += __shfl_xor(l, 32, 64);
  const float inv = 1.0f / l;

  unsigned short* ob = O + (size_t)(qb + c31) * DM + head * DH;
#pragma unroll
  for (int g = 0; g < 4; g++) {
    us4 pk;
    pk[0] = f2bf(o0[4 * g + 0] * inv); pk[1] = f2bf(o0[4 * g + 1] * inv);
    pk[2] = f2bf(o0[4 * g + 2] * inv); pk[3] = f2bf(o0[4 * g + 3] * inv);
    *(us4*)(ob + 8 * g + 4 * hi) = pk;
  }
#pragma unroll
  for (int g = 0; g < 4; g++) {
    us4 pk;
    pk[0] = f2bf(o1[4 * g + 0] * inv); pk[1] = f2bf(o1[4 * g + 1] * inv);
    pk[2] = f2bf(o1[4 * g + 2] * inv); pk[3] = f2bf(o1[4 * g + 3] * inv);
    *(us4*)(ob + 32 + 8 * g + 4 * hi) = pk;
  }
}

extern "C" void kernel_launch(void* const* d_in, const int* in_sizes, int n_in,
                              void* d_out, int out_size, void* d_ws, size_t ws_size,
                              hipStream_t stream) {
  const float* x  = (const float*)d_in[0];
  const float* h  = (const float*)d_in[1];
  const float* Wq = (const float*)d_in[2];
  const float* bq = (const float*)d_in[3];
  const float* Wk = (const float*)d_in[4];
  const float* bk = (const float*)d_in[5];
  const float* Wv = (const float*)d_in[6];
  const float* bv = (const float*)d_in[7];
  const float* Wo = (const float*)d_in[8];
  const float* bo = (const float*)d_in[9];
  float* out = (float*)d_out;

  char* ws = (char*)d_ws;
  const size_t MB = 1 << 20;
  unsigned short* xb    = (unsigned short*)(ws + 0 * MB);   // 8 MB
  unsigned short* wqkvb = (unsigned short*)(ws + 8 * MB);   // 6 MB
  unsigned short* wob   = (unsigned short*)(ws + 14 * MB);  // 2 MB
  unsigned short* Qb    = (unsigned short*)(ws + 16 * MB);  // 8 MB
  unsigned short* Kb    = (unsigned short*)(ws + 24 * MB);  // 8 MB
  unsigned short* Vtb   = (unsigned short*)(ws + 32 * MB);  // 8 MB
  unsigned short* AOb   = (unsigned short*)(ws + 40 * MB);  // 8 MB
  float*          hperm = (float*)(ws + 48 * MB);           // 16 KB

  cvt_kernel<<<4096, 256, 0, stream>>>(x,  xb, (NTOK * DM) / 4);
  cvt_kernel<<<1024, 256, 0, stream>>>(Wq, wqkvb,               (DM * DM) / 4);
  cvt_kernel<<<1024, 256, 0, stream>>>(Wk, wqkvb + DM * DM,     (DM * DM) / 4);
  cvt_kernel<<<1024, 256, 0, stream>>>(Wv, wqkvb + 2 * DM * DM, (DM * DM) / 4);
  cvt_kernel<<<1024, 256, 0, stream>>>(Wo, wob,                 (DM * DM) / 4);
  hprep_kernel<<<16, 256, 0, stream>>>(h, hperm);

  gemm_qkv<<<dim3(24, 32), 256, 0, stream>>>(xb, wqkvb, bq, bk, bv, Qb, Kb, Vtb);

  attn_kernel<<<dim3(512), 256, 0, stream>>>(Qb, Kb, Vtb, hperm, AOb);

  gemm_out<<<dim3(DM / 128, NTOK / 128), 256, 0, stream>>>(AOb, wob, bo, x, out);
}

// Round 6
// 188.046 us; speedup vs baseline: 2.4220x; 1.0894x over previous
//
#include <hip/hip_runtime.h>
#include <hip/hip_bf16.h>
#include <stdint.h>

#define NTOK 4096
#define DM   1024
#define NH   16
#define DH   64
#define SCL  0.1803368801111129f   /* 0.125 * log2(e) */
#define LOG2E 1.4426950408889634f

typedef __attribute__((ext_vector_type(8)))  short bf16x8;
typedef __attribute__((ext_vector_type(4)))  float f32x4;
typedef __attribute__((ext_vector_type(16))) float f32x16;
typedef __attribute__((ext_vector_type(4)))  unsigned short us4;

__device__ inline unsigned short f2bf(float f) {
  union { float f; unsigned int u; } a;
  a.f = f;
  unsigned int u = a.u;
  u += 0x7fffu + ((u >> 16) & 1u);
  return (unsigned short)(u >> 16);
}

__device__ inline unsigned int cvtpk_bf16(float lo, float hi) {
  unsigned int r;
  asm("v_cvt_pk_bf16_f32 %0, %1, %2" : "=v"(r) : "v"(lo), "v"(hi));
  return r;
}

__device__ inline void gload_lds16(const void* gsrc, void* ldst) {
  __builtin_amdgcn_global_load_lds(
      (const __attribute__((address_space(1))) void*)(uintptr_t)gsrc,
      (__attribute__((address_space(3))) void*)(unsigned int)(uintptr_t)ldst,
      16, 0, 0);
}

// ---------------- f32 -> bf16 conversion ----------------
__global__ void cvt_kernel(const float* __restrict__ in,
                           unsigned short* __restrict__ out, int n4) {
  int i = blockIdx.x * 256 + threadIdx.x;
  if (i < n4) {
    float4 v = ((const float4*)in)[i];
    us4 o;
    o[0] = f2bf(v.x); o[1] = f2bf(v.y); o[2] = f2bf(v.z); o[3] = f2bf(v.w);
    ((us4*)out)[i] = o;
  }
}

// ---- h permute: hperm[t*32 + hi*16 + r] = -log2e*h[key]  (MFMA C-init) ----
__global__ void hprep_kernel(const float* __restrict__ h,
                             float* __restrict__ hperm) {
  int i = blockIdx.x * 256 + threadIdx.x;      // 0..4095
  int r  = i & 15;
  int hi = (i >> 4) & 1;
  int t  = i >> 5;
  int key = t * 32 + (r & 3) + 8 * (r >> 2) + 4 * hi;
  hperm[i] = -LOG2E * h[key];                  // GAMMA = 1
}

// ---------------- fused QKV GEMM: A[4096][1024] x Wpack[3072][1024]^T ------
// Q region pre-scaled by SCL so attn logits come out in log2 domain.
__global__ __launch_bounds__(256)
void gemm_qkv(const unsigned short* __restrict__ A,
              const unsigned short* __restrict__ B,
              const float* __restrict__ bq, const float* __restrict__ bk,
              const float* __restrict__ bv,
              unsigned short* __restrict__ Qb, unsigned short* __restrict__ Kb,
              unsigned short* __restrict__ Vt)
{
  const int tid  = threadIdx.x;
  const int wid  = tid >> 6;
  const int lane = tid & 63;
  const int bn = blockIdx.x * 128;
  const int bm = blockIdx.y * 128;
  const int wr = wid >> 1;
  const int wc = wid & 1;

  __shared__ __align__(16) unsigned short As[128 * 32];
  __shared__ __align__(16) unsigned short Bs[128 * 32];

  f32x4 acc[4][4];
#pragma unroll
  for (int i = 0; i < 4; i++)
#pragma unroll
    for (int j = 0; j < 4; j++) acc[i][j] = f32x4{0.f, 0.f, 0.f, 0.f};

  const int fr = lane & 15;
  const int fk = (lane >> 4) * 8;
  const int srow = lane >> 2;
  const int scol = (lane & 3) * 8;

  for (int k0 = 0; k0 < DM; k0 += 32) {
#pragma unroll
    for (int c = 0; c < 2; ++c) {
      const int chunk = wid * 2 + c;
      gload_lds16(A + (size_t)(bm + chunk * 16 + srow) * DM + k0 + scol,
                  &As[chunk * 512]);
      gload_lds16(B + (size_t)(bn + chunk * 16 + srow) * DM + k0 + scol,
                  &Bs[chunk * 512]);
    }
    __syncthreads();
    bf16x8 af[4], bfr[4];
#pragma unroll
    for (int i = 0; i < 4; i++)
      af[i] = *(const bf16x8*)&As[(wr * 64 + i * 16 + fr) * 32 + fk];
#pragma unroll
    for (int j = 0; j < 4; j++)
      bfr[j] = *(const bf16x8*)&Bs[(wc * 64 + j * 16 + fr) * 32 + fk];
#pragma unroll
    for (int i = 0; i < 4; i++)
#pragma unroll
      for (int j = 0; j < 4; j++)
        acc[i][j] = __builtin_amdgcn_mfma_f32_16x16x32_bf16(af[i], bfr[j],
                                                            acc[i][j], 0, 0, 0);
    __syncthreads();
  }

  const int fq = lane >> 4;
  const int region = bn >> 10;                       // 0=Q 1=K 2=V
  const float* bias = (region == 0) ? bq : (region == 1) ? bk : bv;
  const float qscale = (region == 0) ? SCL : 1.0f;
  unsigned short* outp = (region == 0) ? Qb : Kb;
#pragma unroll
  for (int j = 0; j < 4; j++) {
    const int col = bn + wc * 64 + j * 16 + fr;
    const int cl  = col & 1023;
    const float bvx = bias[cl];
#pragma unroll
    for (int i = 0; i < 4; i++) {
      const int row0 = bm + wr * 64 + i * 16 + fq * 4;
      if (region < 2) {
#pragma unroll
        for (int r = 0; r < 4; r++)
          outp[(size_t)(row0 + r) * DM + cl] = f2bf((acc[i][j][r] + bvx) * qscale);
      } else {
        us4 pk;
#pragma unroll
        for (int r = 0; r < 4; r++) pk[r] = f2bf(acc[i][j][r] + bvx);
        *(us4*)&Vt[(size_t)cl * NTOK + row0] = pk;
      }
    }
  }
}

// ---------------- final GEMM: out = AO x Wo^T + bo + x  (f32 out) ----------
__global__ __launch_bounds__(256)
void gemm_out(const unsigned short* __restrict__ A,
              const unsigned short* __restrict__ B,
              const float* __restrict__ bias,
              const float* __restrict__ resid,
              float* __restrict__ Cf)
{
  const int tid  = threadIdx.x;
  const int wid  = tid >> 6;
  const int lane = tid & 63;
  const int bn = blockIdx.x * 128;
  const int bm = blockIdx.y * 128;
  const int wr = wid >> 1;
  const int wc = wid & 1;

  __shared__ __align__(16) unsigned short As[128 * 32];
  __shared__ __align__(16) unsigned short Bs[128 * 32];

  f32x4 acc[4][4];
#pragma unroll
  for (int i = 0; i < 4; i++)
#pragma unroll
    for (int j = 0; j < 4; j++) acc[i][j] = f32x4{0.f, 0.f, 0.f, 0.f};

  const int fr = lane & 15;
  const int fk = (lane >> 4) * 8;
  const int srow = lane >> 2;
  const int scol = (lane & 3) * 8;

  for (int k0 = 0; k0 < DM; k0 += 32) {
#pragma unroll
    for (int c = 0; c < 2; ++c) {
      const int chunk = wid * 2 + c;
      gload_lds16(A + (size_t)(bm + chunk * 16 + srow) * DM + k0 + scol,
                  &As[chunk * 512]);
      gload_lds16(B + (size_t)(bn + chunk * 16 + srow) * DM + k0 + scol,
                  &Bs[chunk * 512]);
    }
    __syncthreads();
    bf16x8 af[4], bfr[4];
#pragma unroll
    for (int i = 0; i < 4; i++)
      af[i] = *(const bf16x8*)&As[(wr * 64 + i * 16 + fr) * 32 + fk];
#pragma unroll
    for (int j = 0; j < 4; j++)
      bfr[j] = *(const bf16x8*)&Bs[(wc * 64 + j * 16 + fr) * 32 + fk];
#pragma unroll
    for (int i = 0; i < 4; i++)
#pragma unroll
      for (int j = 0; j < 4; j++)
        acc[i][j] = __builtin_amdgcn_mfma_f32_16x16x32_bf16(af[i], bfr[j],
                                                            acc[i][j], 0, 0, 0);
    __syncthreads();
  }

  const int fq = lane >> 4;
#pragma unroll
  for (int j = 0; j < 4; j++) {
    const int col = bn + wc * 64 + j * 16 + fr;
    const float bvx = bias[col];
#pragma unroll
    for (int i = 0; i < 4; i++) {
      const int row0 = bm + wr * 64 + i * 16 + fq * 4;
#pragma unroll
      for (int r = 0; r < 4; r++) {
        const size_t idx = (size_t)(row0 + r) * DM + col;
        Cf[idx] = acc[i][j][r] + bvx + resid[idx];
      }
    }
  }
}

// ---------------- attention ------------------------------------------------
// 1024-thread blocks: 16 waves = 4 key-groups (grp) x 4 q-waves (w4).
// Group grp streams keys [grp*1024, grp*1024+1024) through its own 16KB
// double-buffered K/V LDS (64KB total -> 2 blocks/CU = 32 waves/CU).
// K tile: 32 rows x 128B, slot s = dchunk ^ (key&7)  (conflict-free).
// V tile: 32 rows x 128B, row r holds d=r (half 0) and d=r+32 (half 1);
//         slot s = (half*4 + keychunk) ^ (r&7)       (conflict-free).
// Unnormalized exp2 softmax (no max): group merge = pure add of (O, l),
// done in two half-stages through aliased LDS (pad-17 rows, conflict-free).
#define MFMA32(a, b, c) __builtin_amdgcn_mfma_f32_32x32x16_bf16(a, b, c, 0, 0, 0)

__global__ void attn_kernel(const unsigned short* __restrict__ Q,
                            const unsigned short* __restrict__ K,
                            const unsigned short* __restrict__ Vt,
                            const float* __restrict__ hperm,
                            unsigned short* __restrict__ O)
{
  // 512 blocks = 8 XCDs x 64: 2 heads per XCD
  const int wgid = (blockIdx.x & 7) * 64 + (blockIdx.x >> 3);
  const int head = wgid >> 5;
  const int tid  = threadIdx.x;
  const int wid  = tid >> 6;
  const int grp  = wid >> 2;                   // key group 0..3
  const int w4   = wid & 3;                    // q-wave within group
  const int lane = tid & 63;
  const int c31  = lane & 31;
  const int hi   = lane >> 5;
  const int qb   = (wgid & 31) * 128 + w4 * 32;
  const int k0g  = grp * (NTOK / 4);

  __shared__ __align__(16) char lds_raw[65536];
  char* kbase = lds_raw + grp * 16384;         // [2][4096B]
  char* vbase = kbase + 8192;                  // [2][4096B]

  // staging source mapping (pre-swizzled; gload_lds dest is linear)
  const int l8 = lane >> 3;                    // 0..7
  const int l7 = lane & 7;
  const int sq = l7 ^ l8;                      // logical slot for stored slot l7
  const unsigned short* kg =
      K + (size_t)(k0g + w4 * 8 + l8) * DM + head * DH + sq * 8;
  const unsigned short* vg =
      Vt + (size_t)(head * DH + (sq >> 2) * 32 + w4 * 8 + l8) * NTOK
         + k0g + (sq & 3) * 8;

  // fragment read byte-offsets (swizzled, conflict-free)
  int koffB[4], voffB[2][2];
#pragma unroll
  for (int f = 0; f < 4; f++)
    koffB[f] = c31 * 128 + (((f * 2 + hi) ^ (c31 & 7)) << 4);
#pragma unroll
  for (int db = 0; db < 2; db++)
#pragma unroll
    for (int ko = 0; ko < 2; ko++)
      voffB[db][ko] = c31 * 128 + (((db * 4 + ko * 2 + hi) ^ (c31 & 7)) << 4);

  // Q fragments (pre-scaled by SCL in GEMM)
  const unsigned short* qp = Q + (size_t)(qb + c31) * DM + head * DH + hi * 8;
  const bf16x8 qf0 = *(const bf16x8*)(qp);
  const bf16x8 qf1 = *(const bf16x8*)(qp + 16);
  const bf16x8 qf2 = *(const bf16x8*)(qp + 32);
  const bf16x8 qf3 = *(const bf16x8*)(qp + 48);

  f32x16 o0, o1;
#pragma unroll
  for (int i = 0; i < 16; i++) { o0[i] = 0.f; o1[i] = 0.f; }
  float l = 0.f;

  // prologue: stage tile 0 into buffer 0
  gload_lds16(kg, kbase + w4 * 1024);
  gload_lds16(vg, vbase + w4 * 1024);
  __syncthreads();

  int cur = 0;
  const int NT = NTOK / 4 / 32;                // 32 tiles per group
  for (int t = 0; t < NT; ++t) {
    if (t + 1 < NT) {                          // stage next tile (async)
      gload_lds16(kg + (size_t)(t + 1) * 32 * DM,
                  kbase + (cur ^ 1) * 4096 + w4 * 1024);
      gload_lds16(vg + (t + 1) * 32,
                  vbase + (cur ^ 1) * 4096 + w4 * 1024);
    }

    // bias as accumulator init: s = -log2e*h (permuted layout)
    const float* hp = hperm + k0g + t * 32 + hi * 16;
    const float4 b0 = *(const float4*)(hp + 0);
    const float4 b1 = *(const float4*)(hp + 4);
    const float4 b2 = *(const float4*)(hp + 8);
    const float4 b3 = *(const float4*)(hp + 12);
    f32x16 s;
    s[0]  = b0.x; s[1]  = b0.y; s[2]  = b0.z; s[3]  = b0.w;
    s[4]  = b1.x; s[5]  = b1.y; s[6]  = b1.z; s[7]  = b1.w;
    s[8]  = b2.x; s[9]  = b2.y; s[10] = b2.z; s[11] = b2.w;
    s[12] = b3.x; s[13] = b3.y; s[14] = b3.z; s[15] = b3.w;

    const char* Kb = kbase + cur * 4096;
    const char* Vb = vbase + cur * 4096;
    const bf16x8 kf0 = *(const bf16x8*)(Kb + koffB[0]);
    const bf16x8 kf1 = *(const bf16x8*)(Kb + koffB[1]);
    const bf16x8 kf2 = *(const bf16x8*)(Kb + koffB[2]);
    const bf16x8 kf3 = *(const bf16x8*)(Kb + koffB[3]);
    const bf16x8 v00 = *(const bf16x8*)(Vb + voffB[0][0]);
    const bf16x8 v01 = *(const bf16x8*)(Vb + voffB[0][1]);
    const bf16x8 v10 = *(const bf16x8*)(Vb + voffB[1][0]);
    const bf16x8 v11 = *(const bf16x8*)(Vb + voffB[1][1]);

    // S^T[key][q] = K . Q^T  (log2-domain logits, bias pre-added)
    s = MFMA32(kf0, qf0, s);
    s = MFMA32(kf1, qf1, s);
    s = MFMA32(kf2, qf2, s);
    s = MFMA32(kf3, qf3, s);

    // unnormalized softmax: p = 2^s
    float ps[16];
#pragma unroll
    for (int r = 0; r < 16; r++) ps[r] = __builtin_amdgcn_exp2f(s[r]);
    const float rs = (((ps[0] + ps[1]) + (ps[2] + ps[3])) +
                      ((ps[4] + ps[5]) + (ps[6] + ps[7]))) +
                     (((ps[8] + ps[9]) + (ps[10] + ps[11])) +
                      ((ps[12] + ps[13]) + (ps[14] + ps[15])));
    l += rs;

    // pack P^T into B-fragments via cvt_pk + permlane32_swap (T12)
    unsigned int X1 = cvtpk_bf16(ps[0],  ps[1]);
    unsigned int X2 = cvtpk_bf16(ps[2],  ps[3]);
    unsigned int Y1 = cvtpk_bf16(ps[4],  ps[5]);
    unsigned int Y2 = cvtpk_bf16(ps[6],  ps[7]);
    asm("v_permlane32_swap_b32 %0, %1" : "+v"(X1), "+v"(Y1));
    asm("v_permlane32_swap_b32 %0, %1" : "+v"(X2), "+v"(Y2));
    unsigned int X3 = cvtpk_bf16(ps[8],  ps[9]);
    unsigned int X4 = cvtpk_bf16(ps[10], ps[11]);
    unsigned int Y3 = cvtpk_bf16(ps[12], ps[13]);
    unsigned int Y4 = cvtpk_bf16(ps[14], ps[15]);
    asm("v_permlane32_swap_b32 %0, %1" : "+v"(X3), "+v"(Y3));
    asm("v_permlane32_swap_b32 %0, %1" : "+v"(X4), "+v"(Y4));

    union { unsigned int u[4]; bf16x8 v; } P0, P1;
    P0.u[0] = X1; P0.u[1] = X2; P0.u[2] = Y1; P0.u[3] = Y2;
    P1.u[0] = X3; P1.u[1] = X4; P1.u[2] = Y3; P1.u[3] = Y4;

    // O^T[d][q] += V^T . P^T
    o0 = MFMA32(v00, P0.v, o0);
    o0 = MFMA32(v01, P1.v, o0);
    o1 = MFMA32(v10, P0.v, o1);
    o1 = MFMA32(v11, P1.v, o1);

    __syncthreads();   // staged tile landed (vmcnt drain) + all reads done
    cur ^= 1;
  }

  // ---- 4-way group merge (pure add: softmax is unnormalized) ----
  float ov[32];
#pragma unroll
  for (int i = 0; i < 16; i++) { ov[i] = o0[i]; ov[16 + i] = o1[i]; }
  l += __shfl_xor(l, 32, 64);

  float* mO = (float*)lds_raw;                       // [2][4][64][17] f32
  float* mL = (float*)(lds_raw + 34816);             // [2][4][32] f32
  const int g2 = grp >> 1;
  float* slotA = &mO[((g2 * 4 + w4) * 64 + lane) * 17];
  const int liA = (g2 * 4 + w4) * 32 + c31;
  float* slotB = &mO[(w4 * 64 + lane) * 17];
  const int liB = w4 * 32 + c31;

  // stage 1: grp1 -> region0, grp3 -> region1; grp0 += r0, grp2 += r1
#pragma unroll
  for (int H = 0; H < 2; H++) {
    if (grp & 1) {
#pragma unroll
      for (int i = 0; i < 16; i++) slotA[i] = ov[H * 16 + i];
      if (H == 0 && hi == 0) mL[liA] = l;
    }
    __syncthreads();
    if (!(grp & 1)) {
#pragma unroll
      for (int i = 0; i < 16; i++) ov[H * 16 + i] += slotA[i];
      if (H == 0) l += mL[liA];
    }
    __syncthreads();
  }
  // stage 2: grp2 -> region0; grp0 += r0
#pragma unroll
  for (int H = 0; H < 2; H++) {
    if (grp == 2) {
#pragma unroll
      for (int i = 0; i < 16; i++) slotB[i] = ov[H * 16 + i];
      if (H == 0 && hi == 0) mL[liB] = l;
    }
    __syncthreads();
    if (grp == 0) {
#pragma unroll
      for (int i = 0; i < 16; i++) ov[H * 16 + i] += slotB[i];
      if (H == 0) l += mL[liB];
    }
    __syncthreads();
  }

  if (grp == 0) {
    const float inv = 1.0f / l;
    unsigned short* ob = O + (size_t)(qb + c31) * DM + head * DH;
#pragma unroll
    for (int g = 0; g < 4; g++) {
      us4 pk;
      pk[0] = f2bf(ov[4 * g + 0] * inv); pk[1] = f2bf(ov[4 * g + 1] * inv);
      pk[2] = f2bf(ov[4 * g + 2] * inv); pk[3] = f2bf(ov[4 * g + 3] * inv);
      *(us4*)(ob + 8 * g + 4 * hi) = pk;
    }
#pragma unroll
    for (int g = 0; g < 4; g++) {
      us4 pk;
      pk[0] = f2bf(ov[16 + 4 * g + 0] * inv); pk[1] = f2bf(ov[16 + 4 * g + 1] * inv);
      pk[2] = f2bf(ov[16 + 4 * g + 2] * inv); pk[3] = f2bf(ov[16 + 4 * g + 3] * inv);
      *(us4*)(ob + 32 + 8 * g + 4 * hi) = pk;
    }
  }
}

extern "C" void kernel_launch(void* const* d_in, const int* in_sizes, int n_in,
                              void* d_out, int out_size, void* d_ws, size_t ws_size,
                              hipStream_t stream) {
  const float* x  = (const float*)d_in[0];
  const float* h  = (const float*)d_in[1];
  const float* Wq = (const float*)d_in[2];
  const float* bq = (const float*)d_in[3];
  const float* Wk = (const float*)d_in[4];
  const float* bk = (const float*)d_in[5];
  const float* Wv = (const float*)d_in[6];
  const float* bv = (const float*)d_in[7];
  const float* Wo = (const float*)d_in[8];
  const float* bo = (const float*)d_in[9];
  float* out = (float*)d_out;

  char* ws = (char*)d_ws;
  const size_t MB = 1 << 20;
  unsigned short* xb    = (unsigned short*)(ws + 0 * MB);   // 8 MB
  unsigned short* wqkvb = (unsigned short*)(ws + 8 * MB);   // 6 MB
  unsigned short* wob   = (unsigned short*)(ws + 14 * MB);  // 2 MB
  unsigned short* Qb    = (unsigned short*)(ws + 16 * MB);  // 8 MB
  unsigned short* Kb    = (unsigned short*)(ws + 24 * MB);  // 8 MB
  unsigned short* Vtb   = (unsigned short*)(ws + 32 * MB);  // 8 MB
  unsigned short* AOb   = (unsigned short*)(ws + 40 * MB);  // 8 MB
  float*          hperm = (float*)(ws + 48 * MB);           // 16 KB

  cvt_kernel<<<4096, 256, 0, stream>>>(x,  xb, (NTOK * DM) / 4);
  cvt_kernel<<<1024, 256, 0, stream>>>(Wq, wqkvb,               (DM * DM) / 4);
  cvt_kernel<<<1024, 256, 0, stream>>>(Wk, wqkvb + DM * DM,     (DM * DM) / 4);
  cvt_kernel<<<1024, 256, 0, stream>>>(Wv, wqkvb + 2 * DM * DM, (DM * DM) / 4);
  cvt_kernel<<<1024, 256, 0, stream>>>(Wo, wob,                 (DM * DM) / 4);
  hprep_kernel<<<16, 256, 0, stream>>>(h, hperm);

  gemm_qkv<<<dim3(24, 32), 256, 0, stream>>>(xb, wqkvb, bq, bk, bv, Qb, Kb, Vtb);

  attn_kernel<<<dim3(512), 1024, 0, stream>>>(Qb, Kb, Vtb, hperm, AOb);

  gemm_out<<<dim3(DM / 128, NTOK / 128), 256, 0, stream>>>(AOb, wob, bo, x, out);
}

// Round 7
// 169.248 us; speedup vs baseline: 2.6911x; 1.1111x over previous
//
#include <hip/hip_runtime.h>
#include <hip/hip_bf16.h>
#include <stdint.h>

#define NTOK 4096
#define DM   1024
#define NH   16
#define DH   64
#define SCL  0.1803368801111129f   /* 0.125 * log2(e) */
#define LOG2E 1.4426950408889634f

typedef __attribute__((ext_vector_type(8)))  short bf16x8;
typedef __attribute__((ext_vector_type(4)))  float f32x4;
typedef __attribute__((ext_vector_type(16))) float f32x16;
typedef __attribute__((ext_vector_type(4)))  unsigned short us4;

__device__ inline unsigned short f2bf(float f) {
  union { float f; unsigned int u; } a;
  a.f = f;
  unsigned int u = a.u;
  u += 0x7fffu + ((u >> 16) & 1u);
  return (unsigned short)(u >> 16);
}

__device__ inline unsigned int cvtpk_bf16(float lo, float hi) {
  unsigned int r;
  asm("v_cvt_pk_bf16_f32 %0, %1, %2" : "=v"(r) : "v"(lo), "v"(hi));
  return r;
}

__device__ inline void gload_lds16(const void* gsrc, void* ldst) {
  __builtin_amdgcn_global_load_lds(
      (const __attribute__((address_space(1))) void*)(uintptr_t)gsrc,
      (__attribute__((address_space(3))) void*)(unsigned int)(uintptr_t)ldst,
      16, 0, 0);
}

// ------- fused f32->bf16 conversions + hperm prep (single launch) ----------
__global__ void cvt_fused(const float* __restrict__ x,
                          const float* __restrict__ Wq,
                          const float* __restrict__ Wk,
                          const float* __restrict__ Wv,
                          const float* __restrict__ Wo,
                          const float* __restrict__ h,
                          unsigned short* __restrict__ xb,
                          unsigned short* __restrict__ wqkvb,
                          unsigned short* __restrict__ wob,
                          float* __restrict__ hperm) {
  const int b = blockIdx.x;
  if (b >= 8192) {                      // hperm: 16 blocks x 256 = 4096
    int i = (b - 8192) * 256 + threadIdx.x;
    int r  = i & 15;
    int hh = (i >> 4) & 1;
    int t  = i >> 5;
    int key = t * 32 + (r & 3) + 8 * (r >> 2) + 4 * hh;
    hperm[i] = -LOG2E * h[key];         // GAMMA = 1
    return;
  }
  int i = b * 256 + threadIdx.x;        // float4 index over 2M total
  const float* src; unsigned short* dst; int off;
  if (i < 1048576)      { src = x;  dst = xb;                 off = i; }
  else if (i < 1310720) { src = Wq; dst = wqkvb;              off = i - 1048576; }
  else if (i < 1572864) { src = Wk; dst = wqkvb + DM * DM;    off = i - 1310720; }
  else if (i < 1835008) { src = Wv; dst = wqkvb + 2 * DM * DM; off = i - 1572864; }
  else                  { src = Wo; dst = wob;                off = i - 1835008; }
  float4 v = ((const float4*)src)[off];
  us4 o;
  o[0] = f2bf(v.x); o[1] = f2bf(v.y); o[2] = f2bf(v.z); o[3] = f2bf(v.w);
  ((us4*)dst)[off] = o;
}

// ---------------- fused QKV GEMM: A[4096][1024] x Wpack[3072][1024]^T ------
// Q region pre-scaled by SCL so attn logits come out in log2 domain.
__global__ __launch_bounds__(256)
void gemm_qkv(const unsigned short* __restrict__ A,
              const unsigned short* __restrict__ B,
              const float* __restrict__ bq, const float* __restrict__ bk,
              const float* __restrict__ bv,
              unsigned short* __restrict__ Qb, unsigned short* __restrict__ Kb,
              unsigned short* __restrict__ Vt)
{
  const int tid  = threadIdx.x;
  const int wid  = tid >> 6;
  const int lane = tid & 63;
  const int bn = blockIdx.x * 128;
  const int bm = blockIdx.y * 128;
  const int wr = wid >> 1;
  const int wc = wid & 1;

  __shared__ __align__(16) unsigned short As[128 * 32];
  __shared__ __align__(16) unsigned short Bs[128 * 32];

  f32x4 acc[4][4];
#pragma unroll
  for (int i = 0; i < 4; i++)
#pragma unroll
    for (int j = 0; j < 4; j++) acc[i][j] = f32x4{0.f, 0.f, 0.f, 0.f};

  const int fr = lane & 15;
  const int fk = (lane >> 4) * 8;
  const int srow = lane >> 2;
  const int scol = (lane & 3) * 8;

  for (int k0 = 0; k0 < DM; k0 += 32) {
#pragma unroll
    for (int c = 0; c < 2; ++c) {
      const int chunk = wid * 2 + c;
      gload_lds16(A + (size_t)(bm + chunk * 16 + srow) * DM + k0 + scol,
                  &As[chunk * 512]);
      gload_lds16(B + (size_t)(bn + chunk * 16 + srow) * DM + k0 + scol,
                  &Bs[chunk * 512]);
    }
    __syncthreads();
    bf16x8 af[4], bfr[4];
#pragma unroll
    for (int i = 0; i < 4; i++)
      af[i] = *(const bf16x8*)&As[(wr * 64 + i * 16 + fr) * 32 + fk];
#pragma unroll
    for (int j = 0; j < 4; j++)
      bfr[j] = *(const bf16x8*)&Bs[(wc * 64 + j * 16 + fr) * 32 + fk];
#pragma unroll
    for (int i = 0; i < 4; i++)
#pragma unroll
      for (int j = 0; j < 4; j++)
        acc[i][j] = __builtin_amdgcn_mfma_f32_16x16x32_bf16(af[i], bfr[j],
                                                            acc[i][j], 0, 0, 0);
    __syncthreads();
  }

  const int fq = lane >> 4;
  const int region = bn >> 10;                       // 0=Q 1=K 2=V
  const float* bias = (region == 0) ? bq : (region == 1) ? bk : bv;
  const float qscale = (region == 0) ? SCL : 1.0f;
  unsigned short* outp = (region == 0) ? Qb : Kb;
#pragma unroll
  for (int j = 0; j < 4; j++) {
    const int col = bn + wc * 64 + j * 16 + fr;
    const int cl  = col & 1023;
    const float bvx = bias[cl];
#pragma unroll
    for (int i = 0; i < 4; i++) {
      const int row0 = bm + wr * 64 + i * 16 + fq * 4;
      if (region < 2) {
#pragma unroll
        for (int r = 0; r < 4; r++)
          outp[(size_t)(row0 + r) * DM + cl] = f2bf((acc[i][j][r] + bvx) * qscale);
      } else {
        us4 pk;
#pragma unroll
        for (int r = 0; r < 4; r++) pk[r] = f2bf(acc[i][j][r] + bvx);
        *(us4*)&Vt[(size_t)cl * NTOK + row0] = pk;
      }
    }
  }
}

// ---------------- final GEMM: out = AO x Wo^T + bo + x  (f32 out) ----------
__global__ __launch_bounds__(256)
void gemm_out(const unsigned short* __restrict__ A,
              const unsigned short* __restrict__ B,
              const float* __restrict__ bias,
              const float* __restrict__ resid,
              float* __restrict__ Cf)
{
  const int tid  = threadIdx.x;
  const int wid  = tid >> 6;
  const int lane = tid & 63;
  const int bn = blockIdx.x * 128;
  const int bm = blockIdx.y * 128;
  const int wr = wid >> 1;
  const int wc = wid & 1;

  __shared__ __align__(16) unsigned short As[128 * 32];
  __shared__ __align__(16) unsigned short Bs[128 * 32];

  f32x4 acc[4][4];
#pragma unroll
  for (int i = 0; i < 4; i++)
#pragma unroll
    for (int j = 0; j < 4; j++) acc[i][j] = f32x4{0.f, 0.f, 0.f, 0.f};

  const int fr = lane & 15;
  const int fk = (lane >> 4) * 8;
  const int srow = lane >> 2;
  const int scol = (lane & 3) * 8;

  for (int k0 = 0; k0 < DM; k0 += 32) {
#pragma unroll
    for (int c = 0; c < 2; ++c) {
      const int chunk = wid * 2 + c;
      gload_lds16(A + (size_t)(bm + chunk * 16 + srow) * DM + k0 + scol,
                  &As[chunk * 512]);
      gload_lds16(B + (size_t)(bn + chunk * 16 + srow) * DM + k0 + scol,
                  &Bs[chunk * 512]);
    }
    __syncthreads();
    bf16x8 af[4], bfr[4];
#pragma unroll
    for (int i = 0; i < 4; i++)
      af[i] = *(const bf16x8*)&As[(wr * 64 + i * 16 + fr) * 32 + fk];
#pragma unroll
    for (int j = 0; j < 4; j++)
      bfr[j] = *(const bf16x8*)&Bs[(wc * 64 + j * 16 + fr) * 32 + fk];
#pragma unroll
    for (int i = 0; i < 4; i++)
#pragma unroll
      for (int j = 0; j < 4; j++)
        acc[i][j] = __builtin_amdgcn_mfma_f32_16x16x32_bf16(af[i], bfr[j],
                                                            acc[i][j], 0, 0, 0);
    __syncthreads();
  }

  const int fq = lane >> 4;
#pragma unroll
  for (int j = 0; j < 4; j++) {
    const int col = bn + wc * 64 + j * 16 + fr;
    const float bvx = bias[col];
#pragma unroll
    for (int i = 0; i < 4; i++) {
      const int row0 = bm + wr * 64 + i * 16 + fq * 4;
#pragma unroll
      for (int r = 0; r < 4; r++) {
        const size_t idx = (size_t)(row0 + r) * DM + col;
        Cf[idx] = acc[i][j][r] + bvx + resid[idx];
      }
    }
  }
}

// ---------------- attention ------------------------------------------------
// 512-thread blocks: 8 waves = 2 key-groups (grp) x 4 q-waves (w4).
// Each wave owns 64 q rows (two 32-q MFMA blocks A,B sharing every K/V
// fragment read -> LDS traffic halved). Group grp streams keys
// [grp*2048, grp*2048+2048) through a 16KB double-buffered K/V LDS region.
// Tiles are [16 rows][16 slots x 16B] with slot = logical ^ (row&15):
// any 8/16-lane phase hits distinct slots -> zero bank conflicts.
// Staging is linear global_load_lds with the inverse permutation applied to
// the per-lane GLOBAL source address (m173). Softmax is unnormalized exp2
// (Q pre-scaled, -log2e*h as MFMA C-init). 2-way group merge = pure add.
#define MFMA32(a, b, c) __builtin_amdgcn_mfma_f32_32x32x16_bf16(a, b, c, 0, 0, 0)

__global__ __launch_bounds__(512)
void attn_kernel(const unsigned short* __restrict__ Q,
                 const unsigned short* __restrict__ K,
                 const unsigned short* __restrict__ Vt,
                 const float* __restrict__ hperm,
                 unsigned short* __restrict__ O)
{
  // 256 blocks = 8 XCDs x 32: 2 heads per XCD
  const int wgid = (blockIdx.x & 7) * 32 + (blockIdx.x >> 3);
  const int head = wgid >> 4;
  const int qblk = wgid & 15;
  const int tid  = threadIdx.x;
  const int wid  = tid >> 6;
  const int grp  = wid >> 2;                   // key group 0..1
  const int w4   = wid & 3;                    // q-wave within group
  const int lane = tid & 63;
  const int c31  = lane & 31;
  const int hi   = lane >> 5;
  const int qwb  = qblk * 256 + w4 * 64;
  const int k0g  = grp * 2048;

  __shared__ __align__(16) char lds_raw[34816];
  char* kbase = lds_raw + grp * 16384;         // [2 buf][4096B]
  char* vbase = kbase + 8192;

  // ---- staging source (pre-swizzled; gload_lds dest linear) ----
  // K tile [16][16]: row r holds keys {r, r+16}; logical slot q = khalf*8+dc;
  // stored slot s = q ^ r.  V tile [16][16]: row r holds d in {r,r+16,r+32,
  // r+48}; logical q = (d>>4)*4 + kc; stored s = q ^ r.
  const int srow = w4 * 4 + (lane >> 4);       // 0..15
  const int ssl  = lane & 15;
  const int kq   = ssl ^ srow;
  const int kkey = srow + 16 * (kq >> 3);
  const unsigned short* kg =
      K + (size_t)(k0g + kkey) * DM + head * DH + (kq & 7) * 8;
  const int vd = ((kq) >> 2) * 16 + srow;
  const unsigned short* vg =
      Vt + (size_t)(head * DH + vd) * NTOK + k0g + (kq & 3) * 8;

  // ---- fragment read byte-offsets (swizzled, conflict-free) ----
  const int fr15 = c31 & 15;
  const int fkh  = c31 >> 4;
  int koffB[4], voffB[2][2];
#pragma unroll
  for (int f = 0; f < 4; f++)
    koffB[f] = fr15 * 256 + (((fkh * 8 + f * 2 + hi) ^ fr15) << 4);
#pragma unroll
  for (int db = 0; db < 2; db++)
#pragma unroll
    for (int ko = 0; ko < 2; ko++)
      voffB[db][ko] =
          fr15 * 256 + ((((db * 2 + fkh) * 4 + ko * 2 + hi) ^ fr15) << 4);

  // ---- Q fragments (pre-scaled by SCL in GEMM): two 32-q blocks ----
  const unsigned short* qpA = Q + (size_t)(qwb + c31) * DM + head * DH + hi * 8;
  const unsigned short* qpB = qpA + (size_t)32 * DM;
  const bf16x8 qa0 = *(const bf16x8*)(qpA);
  const bf16x8 qa1 = *(const bf16x8*)(qpA + 16);
  const bf16x8 qa2 = *(const bf16x8*)(qpA + 32);
  const bf16x8 qa3 = *(const bf16x8*)(qpA + 48);
  const bf16x8 qb0 = *(const bf16x8*)(qpB);
  const bf16x8 qb1 = *(const bf16x8*)(qpB + 16);
  const bf16x8 qb2 = *(const bf16x8*)(qpB + 32);
  const bf16x8 qb3 = *(const bf16x8*)(qpB + 48);

  f32x16 o0A, o1A, o0B, o1B;
#pragma unroll
  for (int i = 0; i < 16; i++) { o0A[i] = 0.f; o1A[i] = 0.f; o0B[i] = 0.f; o1B[i] = 0.f; }
  float lA = 0.f, lB = 0.f;

  // prologue: stage tile 0 into buffer 0
  gload_lds16(kg, kbase + w4 * 1024);
  gload_lds16(vg, vbase + w4 * 1024);
  __syncthreads();

  int cur = 0;
  const int NT = 2048 / 32;                    // 64 tiles per group
  for (int t = 0; t < NT; ++t) {
    if (t + 1 < NT) {
      gload_lds16(kg + (size_t)(t + 1) * 32 * DM,
                  kbase + (cur ^ 1) * 4096 + w4 * 1024);
      gload_lds16(vg + (t + 1) * 32,
                  vbase + (cur ^ 1) * 4096 + w4 * 1024);
    }

    // bias (C-init): s = -log2e*h in permuted layout
    const float* hp = hperm + k0g + t * 32 + hi * 16;
    const float4 b0 = *(const float4*)(hp + 0);
    const float4 b1 = *(const float4*)(hp + 4);
    const float4 b2 = *(const float4*)(hp + 8);
    const float4 b3 = *(const float4*)(hp + 12);

    const char* Kb = kbase + cur * 4096;
    const char* Vb = vbase + cur * 4096;
    const bf16x8 kf0 = *(const bf16x8*)(Kb + koffB[0]);
    const bf16x8 kf1 = *(const bf16x8*)(Kb + koffB[1]);
    const bf16x8 kf2 = *(const bf16x8*)(Kb + koffB[2]);
    const bf16x8 kf3 = *(const bf16x8*)(Kb + koffB[3]);

    f32x16 sA, sB;
    sA[0]  = b0.x; sA[1]  = b0.y; sA[2]  = b0.z; sA[3]  = b0.w;
    sA[4]  = b1.x; sA[5]  = b1.y; sA[6]  = b1.z; sA[7]  = b1.w;
    sA[8]  = b2.x; sA[9]  = b2.y; sA[10] = b2.z; sA[11] = b2.w;
    sA[12] = b3.x; sA[13] = b3.y; sA[14] = b3.z; sA[15] = b3.w;
    sB = sA;

    sA = MFMA32(kf0, qa0, sA);
    sA = MFMA32(kf1, qa1, sA);
    sA = MFMA32(kf2, qa2, sA);
    sA = MFMA32(kf3, qa3, sA);
    sB = MFMA32(kf0, qb0, sB);
    sB = MFMA32(kf1, qb1, sB);
    sB = MFMA32(kf2, qb2, sB);
    sB = MFMA32(kf3, qb3, sB);

    const bf16x8 v00 = *(const bf16x8*)(Vb + voffB[0][0]);
    const bf16x8 v01 = *(const bf16x8*)(Vb + voffB[0][1]);
    const bf16x8 v10 = *(const bf16x8*)(Vb + voffB[1][0]);
    const bf16x8 v11 = *(const bf16x8*)(Vb + voffB[1][1]);

    // softmax A (unnormalized)
    float ps[16];
#pragma unroll
    for (int r = 0; r < 16; r++) ps[r] = __builtin_amdgcn_exp2f(sA[r]);
    lA += (((ps[0] + ps[1]) + (ps[2] + ps[3])) +
           ((ps[4] + ps[5]) + (ps[6] + ps[7]))) +
          (((ps[8] + ps[9]) + (ps[10] + ps[11])) +
           ((ps[12] + ps[13]) + (ps[14] + ps[15])));
    unsigned int X1 = cvtpk_bf16(ps[0],  ps[1]);
    unsigned int X2 = cvtpk_bf16(ps[2],  ps[3]);
    unsigned int Y1 = cvtpk_bf16(ps[4],  ps[5]);
    unsigned int Y2 = cvtpk_bf16(ps[6],  ps[7]);
    asm("v_permlane32_swap_b32 %0, %1" : "+v"(X1), "+v"(Y1));
    asm("v_permlane32_swap_b32 %0, %1" : "+v"(X2), "+v"(Y2));
    unsigned int X3 = cvtpk_bf16(ps[8],  ps[9]);
    unsigned int X4 = cvtpk_bf16(ps[10], ps[11]);
    unsigned int Y3 = cvtpk_bf16(ps[12], ps[13]);
    unsigned int Y4 = cvtpk_bf16(ps[14], ps[15]);
    asm("v_permlane32_swap_b32 %0, %1" : "+v"(X3), "+v"(Y3));
    asm("v_permlane32_swap_b32 %0, %1" : "+v"(X4), "+v"(Y4));
    union { unsigned int u[4]; bf16x8 v; } PA0, PA1;
    PA0.u[0] = X1; PA0.u[1] = X2; PA0.u[2] = Y1; PA0.u[3] = Y2;
    PA1.u[0] = X3; PA1.u[1] = X4; PA1.u[2] = Y3; PA1.u[3] = Y4;

    // softmax B
#pragma unroll
    for (int r = 0; r < 16; r++) ps[r] = __builtin_amdgcn_exp2f(sB[r]);
    lB += (((ps[0] + ps[1]) + (ps[2] + ps[3])) +
           ((ps[4] + ps[5]) + (ps[6] + ps[7]))) +
          (((ps[8] + ps[9]) + (ps[10] + ps[11])) +
           ((ps[12] + ps[13]) + (ps[14] + ps[15])));
    X1 = cvtpk_bf16(ps[0],  ps[1]);
    X2 = cvtpk_bf16(ps[2],  ps[3]);
    Y1 = cvtpk_bf16(ps[4],  ps[5]);
    Y2 = cvtpk_bf16(ps[6],  ps[7]);
    asm("v_permlane32_swap_b32 %0, %1" : "+v"(X1), "+v"(Y1));
    asm("v_permlane32_swap_b32 %0, %1" : "+v"(X2), "+v"(Y2));
    X3 = cvtpk_bf16(ps[8],  ps[9]);
    X4 = cvtpk_bf16(ps[10], ps[11]);
    Y3 = cvtpk_bf16(ps[12], ps[13]);
    Y4 = cvtpk_bf16(ps[14], ps[15]);
    asm("v_permlane32_swap_b32 %0, %1" : "+v"(X3), "+v"(Y3));
    asm("v_permlane32_swap_b32 %0, %1" : "+v"(X4), "+v"(Y4));
    union { unsigned int u[4]; bf16x8 v; } PB0, PB1;
    PB0.u[0] = X1; PB0.u[1] = X2; PB0.u[2] = Y1; PB0.u[3] = Y2;
    PB1.u[0] = X3; PB1.u[1] = X4; PB1.u[2] = Y3; PB1.u[3] = Y4;

    // PV (V frags shared by A and B)
    o0A = MFMA32(v00, PA0.v, o0A);
    o0A = MFMA32(v01, PA1.v, o0A);
    o1A = MFMA32(v10, PA0.v, o1A);
    o1A = MFMA32(v11, PA1.v, o1A);
    o0B = MFMA32(v00, PB0.v, o0B);
    o0B = MFMA32(v01, PB1.v, o0B);
    o1B = MFMA32(v10, PB0.v, o1B);
    o1B = MFMA32(v11, PB1.v, o1B);

    __syncthreads();
    cur ^= 1;
  }

  lA += __shfl_xor(lA, 32, 64);
  lB += __shfl_xor(lB, 32, 64);

  // ---- 2-way group merge (pure add) through LDS, pad-33 rows ----
  float* mo = (float*)lds_raw;                       // [4][64][33]
  float* mL = (float*)(lds_raw + 33792);             // [4][2][32]
  float* row = &mo[(w4 * 64 + lane) * 33];
#pragma unroll
  for (int half = 0; half < 2; half++) {
    __syncthreads();
    if (grp == 1) {
      const f32x16& hA = half ? o1A : o0A;
      const f32x16& hB = half ? o1B : o0B;
#pragma unroll
      for (int i = 0; i < 16; i++) { row[i] = hA[i]; row[16 + i] = hB[i]; }
      if (half == 0 && hi == 0) {
        mL[(w4 * 2 + 0) * 32 + c31] = lA;
        mL[(w4 * 2 + 1) * 32 + c31] = lB;
      }
    }
    __syncthreads();
    if (grp == 0) {
      f32x16& hA = half ? o1A : o0A;
      f32x16& hB = half ? o1B : o0B;
#pragma unroll
      for (int i = 0; i < 16; i++) { hA[i] += row[i]; hB[i] += row[16 + i]; }
      if (half == 0) {
        lA += mL[(w4 * 2 + 0) * 32 + c31];
        lB += mL[(w4 * 2 + 1) * 32 + c31];
      }
    }
  }

  if (grp == 0) {
    const float invA = 1.0f / lA;
    const float invB = 1.0f / lB;
    unsigned short* obA = O + (size_t)(qwb + c31) * DM + head * DH;
    unsigned short* obB = obA + (size_t)32 * DM;
#pragma unroll
    for (int g = 0; g < 4; g++) {
      us4 pk;
      pk[0] = f2bf(o0A[4 * g + 0] * invA); pk[1] = f2bf(o0A[4 * g + 1] * invA);
      pk[2] = f2bf(o0A[4 * g + 2] * invA); pk[3] = f2bf(o0A[4 * g + 3] * invA);
      *(us4*)(obA + 8 * g + 4 * hi) = pk;
      pk[0] = f2bf(o1A[4 * g + 0] * invA); pk[1] = f2bf(o1A[4 * g + 1] * invA);
      pk[2] = f2bf(o1A[4 * g + 2] * invA); pk[3] = f2bf(o1A[4 * g + 3] * invA);
      *(us4*)(obA + 32 + 8 * g + 4 * hi) = pk;
      pk[0] = f2bf(o0B[4 * g + 0] * invB); pk[1] = f2bf(o0B[4 * g + 1] * invB);
      pk[2] = f2bf(o0B[4 * g + 2] * invB); pk[3] = f2bf(o0B[4 * g + 3] * invB);
      *(us4*)(obB + 8 * g + 4 * hi) = pk;
      pk[0] = f2bf(o1B[4 * g + 0] * invB); pk[1] = f2bf(o1B[4 * g + 1] * invB);
      pk[2] = f2bf(o1B[4 * g + 2] * invB); pk[3] = f2bf(o1B[4 * g + 3] * invB);
      *(us4*)(obB + 32 + 8 * g + 4 * hi) = pk;
    }
  }
}

extern "C" void kernel_launch(void* const* d_in, const int* in_sizes, int n_in,
                              void* d_out, int out_size, void* d_ws, size_t ws_size,
                              hipStream_t stream) {
  const float* x  = (const float*)d_in[0];
  const float* h  = (const float*)d_in[1];
  const float* Wq = (const float*)d_in[2];
  const float* bq = (const float*)d_in[3];
  const float* Wk = (const float*)d_in[4];
  const float* bk = (const float*)d_in[5];
  const float* Wv = (const float*)d_in[6];
  const float* bv = (const float*)d_in[7];
  const float* Wo = (const float*)d_in[8];
  const float* bo = (const float*)d_in[9];
  float* out = (float*)d_out;

  char* ws = (char*)d_ws;
  const size_t MB = 1 << 20;
  unsigned short* xb    = (unsigned short*)(ws + 0 * MB);   // 8 MB
  unsigned short* wqkvb = (unsigned short*)(ws + 8 * MB);   // 6 MB
  unsigned short* wob   = (unsigned short*)(ws + 14 * MB);  // 2 MB
  unsigned short* Qb    = (unsigned short*)(ws + 16 * MB);  // 8 MB
  unsigned short* Kb    = (unsigned short*)(ws + 24 * MB);  // 8 MB
  unsigned short* Vtb   = (unsigned short*)(ws + 32 * MB);  // 8 MB
  unsigned short* AOb   = (unsigned short*)(ws + 40 * MB);  // 8 MB
  float*          hperm = (float*)(ws + 48 * MB);           // 16 KB

  cvt_fused<<<8208, 256, 0, stream>>>(x, Wq, Wk, Wv, Wo, h,
                                      xb, wqkvb, wob, hperm);

  gemm_qkv<<<dim3(24, 32), 256, 0, stream>>>(xb, wqkvb, bq, bk, bv, Qb, Kb, Vtb);

  attn_kernel<<<dim3(256), 512, 0, stream>>>(Qb, Kb, Vtb, hperm, AOb);

  gemm_out<<<dim3(DM / 128, NTOK / 128), 256, 0, stream>>>(AOb, wob, bo, x, out);
}